// Round 7
// baseline (501.403 us; speedup 1.0000x reference)
//
#include <hip/hip_runtime.h>

// (B, CQ, CR, HID, H, W) = (8, 1024, 512, 256, 48, 48)
#define BB   8
#define PP   2304
#define CQD  1024
#define CRD  512
#define HIDD 256
#define GB   4       // batches per group (P scratch reuse)
#define NKB  36      // 64-key stat blocks per row
#define LOG2E 1.4426950408889634f

typedef float f32x4 __attribute__((ext_vector_type(4)));
typedef __bf16 bf16x8 __attribute__((ext_vector_type(8)));
typedef unsigned short u16x8 __attribute__((ext_vector_type(8)));
typedef unsigned short u16x4 __attribute__((ext_vector_type(4)));
typedef unsigned int u32x4 __attribute__((ext_vector_type(4)));
typedef unsigned short ushort_t;

__device__ __forceinline__ unsigned short f2bf(float f) {
  unsigned int u = __float_as_uint(f);
  u += 0x7fffu + ((u >> 16) & 1u);  // RNE
  return (unsigned short)(u >> 16);
}
__device__ __forceinline__ float bf2f(unsigned short h) {
  return __uint_as_float(((unsigned int)h) << 16);
}
__device__ __forceinline__ bf16x8 load_bf8(const ushort_t* p) {
  return *(const bf16x8*)p;
}
__device__ __forceinline__ void async16(const void* g, void* l) {
  __builtin_amdgcn_global_load_lds(
      (const __attribute__((address_space(1))) unsigned int*)g,
      (__attribute__((address_space(3))) unsigned int*)l, 16, 0, 0);
}

#define MFMA16(a, b, c) __builtin_amdgcn_mfma_f32_16x16x32_bf16((a), (b), (c), 0, 0, 0)

// ---------------------------------------------------------------------------
// W cast: W[o][c] f32 -> split bf16 Wh/Wl (same layout). One-shot.
// ---------------------------------------------------------------------------
__global__ __launch_bounds__(256) void wcast_kernel(
    const float* __restrict__ W, ushort_t* __restrict__ Wh,
    ushort_t* __restrict__ Wl) {
  const size_t i = ((size_t)blockIdx.x * 256 + threadIdx.x) * 8;
  float4 a = *(const float4*)(W + i);
  float4 b2 = *(const float4*)(W + i + 4);
  float av[8] = {a.x, a.y, a.z, a.w, b2.x, b2.y, b2.z, b2.w};
  u16x8 h, l;
#pragma unroll
  for (int j = 0; j < 8; ++j) {
    unsigned short hh = f2bf(av[j]);
    h[j] = hh;
    l[j] = f2bf(av[j] - bf2f(hh));
  }
  *(u16x8*)(Wh + i) = h;
  *(u16x8*)(Wl + i) = l;
}

// ---------------------------------------------------------------------------
// X transpose-cast: X[b][c][p] f32 -> Xth/Xtl[b*P+p][c] split bf16.
// WV: additionally emit V[b][c][p] = bf16(X) (fuses old cast_v read).
// ---------------------------------------------------------------------------
template <int C, bool WV>
__global__ __launch_bounds__(256) void tcast_kernel(
    const float* __restrict__ X, ushort_t* __restrict__ Th,
    ushort_t* __restrict__ Tl, ushort_t* __restrict__ Vb) {
  const int b = blockIdx.z;
  const int p0 = blockIdx.x * 64;
  const int c0 = blockIdx.y * 64;
  const int tid = threadIdx.x;

  __shared__ unsigned int HL[64][66];  // [p_local][c_local] = h | l<<16

  {
    const int cr = tid >> 2;  // c row 0..63
    const int ch = tid & 3;   // p chunk of 16
    const float* src = X + ((size_t)b * C + c0 + cr) * PP + p0 + ch * 16;
    u16x8 vcast[2];
#pragma unroll
    for (int i = 0; i < 4; ++i) {
      float4 v = *(const float4*)(src + i * 4);
      float vv[4] = {v.x, v.y, v.z, v.w};
#pragma unroll
      for (int k = 0; k < 4; ++k) {
        unsigned short h = f2bf(vv[k]);
        unsigned short l = f2bf(vv[k] - bf2f(h));
        HL[ch * 16 + i * 4 + k][cr] =
            (unsigned int)h | ((unsigned int)l << 16);
        if (WV) vcast[i >> 1][(i & 1) * 4 + k] = h;
      }
    }
    if (WV) {
      ushort_t* vd = Vb + ((size_t)b * C + c0 + cr) * PP + p0 + ch * 16;
      *(u16x8*)(vd) = vcast[0];
      *(u16x8*)(vd + 8) = vcast[1];
    }
  }
  __syncthreads();
  {
    const int pr = tid >> 2;  // p row 0..63
    const int pc = tid & 3;   // c chunk of 16
    u16x8 hv[2], lv[2];
#pragma unroll
    for (int m = 0; m < 2; ++m)
#pragma unroll
      for (int j = 0; j < 8; ++j) {
        unsigned int wb = HL[pr][pc * 16 + m * 8 + j];
        hv[m][j] = (unsigned short)(wb & 0xffffu);
        lv[m][j] = (unsigned short)(wb >> 16);
      }
    const size_t obase = ((size_t)b * PP + p0 + pr) * C + c0 + pc * 16;
    *(u16x8*)(Th + obase) = hv[0];
    *(u16x8*)(Th + obase + 8) = hv[1];
    *(u16x8*)(Tl + obase) = lv[0];
    *(u16x8*)(Tl + obase + 8) = lv[1];
  }
}

// ---------------------------------------------------------------------------
// Projection GEMM: Out[bp][o] = sum_c W[o][c] X[bp][c], 3-term split-bf16.
// Tile 128bp x 64o -> grid 576 (2.25 blocks/CU); LDS 48 KB -> 3 blocks/CU.
// All 3 terms per K-step (24 MFMA/wave/step). Source-swizzled staging
// (<=2-way LDS conflicts). XCD-chunk swizzled grid.
// ---------------------------------------------------------------------------
template <int C>
__global__ __launch_bounds__(256, 3) void projgemm_kernel(
    const ushort_t* __restrict__ Wh, const ushort_t* __restrict__ Wl,
    const ushort_t* __restrict__ Xh, const ushort_t* __restrict__ Xl,
    const float* __restrict__ bias, ushort_t* __restrict__ Oh,
    ushort_t* __restrict__ Ol) {
  // grid 144 x 4 = 576, %8==0 -> chunk 72 XCD swizzle
  const int lin = blockIdx.x + 144 * blockIdx.y;
  const int o = (lin & 7) * 72 + (lin >> 3);
  const int bp0 = (o % 144) * 128;
  const int o0 = (o / 144) * 64;

  const int tid = threadIdx.x;
  const int lane = tid & 63;
  const int w = tid >> 6;
  const int l15 = lane & 15;
  const int quad = lane >> 4;
  const int wm = w & 1;   // o half (2 x 32)
  const int wn = w >> 1;  // bp half (2 x 64)

  __shared__ __align__(16) ushort_t Wt[2][2][64][32];   // 16 KB
  __shared__ __align__(16) ushort_t Xt[2][2][128][32];  // 32 KB

  f32x4 acc[2][4] = {};

  const ushort_t* Wb[2] = {Wh + (size_t)o0 * C, Wl + (size_t)o0 * C};
  const ushort_t* Xb[2] = {Xh + (size_t)bp0 * C, Xl + (size_t)bp0 * C};

  const int r16 = lane >> 2;
  const int c4 = lane & 3;
  const int swz = c4 ^ ((r16 >> 1) & 3);  // source chunk swizzle

  // 24 staging regions of 16 rows: 0-7 = W (2 tensors x 4), 8-23 = X (2 x 8).
  auto stage = [&](int cs, int buf) {
    const int ko = cs * 32;
#pragma unroll
    for (int j = 0; j < 6; ++j) {
      const int reg = w * 6 + j;
      if (reg < 8) {
        const int t = reg >> 2, rg = reg & 3;
        async16(Wb[t] + (size_t)(rg * 16 + r16) * C + ko + swz * 8,
                &Wt[buf][t][rg * 16][0]);
      } else {
        const int t = (reg - 8) >> 3, rg = (reg - 8) & 7;
        async16(Xb[t] + (size_t)(rg * 16 + r16) * C + ko + swz * 8,
                &Xt[buf][t][rg * 16][0]);
      }
    }
  };

  stage(0, 0);
  __syncthreads();

  const int NS = C / 32;
  for (int cs = 0; cs < NS; ++cs) {
    const int buf = cs & 1;
    if (cs + 1 < NS) stage(cs + 1, buf ^ 1);

    bf16x8 ah[2], al[2], bh[4], bl[4];
#pragma unroll
    for (int mt = 0; mt < 2; ++mt) {
      const int row = wm * 32 + mt * 16 + l15;
      const int g = (quad ^ ((row >> 1) & 3)) * 8;
      ah[mt] = load_bf8(&Wt[buf][0][row][g]);
      al[mt] = load_bf8(&Wt[buf][1][row][g]);
    }
#pragma unroll
    for (int nt = 0; nt < 4; ++nt) {
      const int row = wn * 64 + nt * 16 + l15;
      const int g = (quad ^ ((row >> 1) & 3)) * 8;
      bh[nt] = load_bf8(&Xt[buf][0][row][g]);
      bl[nt] = load_bf8(&Xt[buf][1][row][g]);
    }
#pragma unroll
    for (int mt = 0; mt < 2; ++mt)
#pragma unroll
      for (int nt = 0; nt < 4; ++nt) {
        acc[mt][nt] = MFMA16(ah[mt], bh[nt], acc[mt][nt]);
        acc[mt][nt] = MFMA16(al[mt], bh[nt], acc[mt][nt]);
        acc[mt][nt] = MFMA16(ah[mt], bl[nt], acc[mt][nt]);
      }
    __syncthreads();
  }

  // epilogue: bias + split-cast, store Oh/Ol at [bp][o]
#pragma unroll
  for (int mt = 0; mt < 2; ++mt) {
    const int ob = o0 + wm * 32 + mt * 16 + quad * 4;
    float bv[4];
#pragma unroll
    for (int r = 0; r < 4; ++r) bv[r] = bias[ob + r];
#pragma unroll
    for (int nt = 0; nt < 4; ++nt) {
      const int bp = bp0 + wn * 64 + nt * 16 + l15;
      u16x4 hs, ls;
#pragma unroll
      for (int r = 0; r < 4; ++r) {
        float v2 = acc[mt][nt][r] + bv[r];
        unsigned short h = f2bf(v2);
        hs[r] = h;
        ls[r] = f2bf(v2 - bf2f(h));
      }
      const size_t base = (size_t)bp * HIDD + ob;
      *(u16x4*)(Oh + base) = hs;
      *(u16x4*)(Ol + base) = ls;
    }
  }
}

// ---------------------------------------------------------------------------
// Old projection (kept ONLY for the small-workspace fallback path).
// ---------------------------------------------------------------------------
template <int C>
__global__ __launch_bounds__(256) void proj_kernel(
    const float* __restrict__ X, const float* __restrict__ W,
    const float* __restrict__ bias, ushort_t* __restrict__ Oh,
    ushort_t* __restrict__ Ol) {
  const int b = blockIdx.z;
  const int p0 = blockIdx.y * 64;
  const int o0 = blockIdx.x * 64;
  const int tid = threadIdx.x;
  const int lane = tid & 63;
  const int wave = tid >> 6;
  const int wm = wave & 1;
  const int wn = wave >> 1;
  const int l15 = lane & 15;
  const int quad = lane >> 4;

  __shared__ ushort_t Xh[64][40];
  __shared__ ushort_t Xl[64][40];

  f32x4 acc[2][2] = {};
  const float* Xb = X + (size_t)b * C * PP;
  const int cc = tid >> 3;
  const int ppo = (tid & 7) * 8;

  for (int c0 = 0; c0 < C; c0 += 32) {
    const float* src = Xb + (size_t)(c0 + cc) * PP + p0 + ppo;
    float4 v0 = *(const float4*)(src);
    float4 v1 = *(const float4*)(src + 4);
    float vv[8] = {v0.x, v0.y, v0.z, v0.w, v1.x, v1.y, v1.z, v1.w};
#pragma unroll
    for (int j = 0; j < 8; ++j) {
      unsigned short h = f2bf(vv[j]);
      Xh[ppo + j][cc] = h;
      Xl[ppo + j][cc] = f2bf(vv[j] - bf2f(h));
    }
    __syncthreads();

    bf16x8 wh[2], wl[2];
#pragma unroll
    for (int mt = 0; mt < 2; ++mt) {
      const float* wsrc =
          W + (size_t)(o0 + wm * 32 + mt * 16 + l15) * C + c0 + quad * 8;
      float4 a0 = *(const float4*)(wsrc);
      float4 a1 = *(const float4*)(wsrc + 4);
      float av[8] = {a0.x, a0.y, a0.z, a0.w, a1.x, a1.y, a1.z, a1.w};
      u16x8 hh, ll;
#pragma unroll
      for (int j = 0; j < 8; ++j) {
        unsigned short h = f2bf(av[j]);
        hh[j] = h;
        ll[j] = f2bf(av[j] - bf2f(h));
      }
      wh[mt] = __builtin_bit_cast(bf16x8, hh);
      wl[mt] = __builtin_bit_cast(bf16x8, ll);
    }

#pragma unroll
    for (int nt = 0; nt < 2; ++nt) {
      const int pr = wn * 32 + nt * 16 + l15;
      bf16x8 xh = load_bf8(&Xh[pr][quad * 8]);
      bf16x8 xl = load_bf8(&Xl[pr][quad * 8]);
#pragma unroll
      for (int mt = 0; mt < 2; ++mt) {
        acc[mt][nt] = MFMA16(wh[mt], xh, acc[mt][nt]);
        acc[mt][nt] = MFMA16(wl[mt], xh, acc[mt][nt]);
        acc[mt][nt] = MFMA16(wh[mt], xl, acc[mt][nt]);
      }
    }
    __syncthreads();
  }

#pragma unroll
  for (int mt = 0; mt < 2; ++mt) {
    const int ob = o0 + wm * 32 + mt * 16 + quad * 4;
#pragma unroll
    for (int nt = 0; nt < 2; ++nt) {
      const int p = p0 + wn * 32 + nt * 16 + l15;
      u16x4 hs, ls;
#pragma unroll
      for (int r = 0; r < 4; ++r) {
        float v = acc[mt][nt][r] + bias[ob + r];
        unsigned short h = f2bf(v);
        hs[r] = h;
        ls[r] = f2bf(v - bf2f(h));
      }
      const size_t base = ((size_t)b * PP + p) * HIDD + ob;
      *(u16x4*)(Oh + base) = hs;
      *(u16x4*)(Ol + base) = ls;
    }
  }
}

__global__ void cast_v_kernel(const float* __restrict__ X,
                              ushort_t* __restrict__ V) {
  const size_t i = ((size_t)blockIdx.x * 256 + threadIdx.x) * 4;
  float4 v = *(const float4*)(X + i);
  u16x4 o;
  o[0] = f2bf(v.x); o[1] = f2bf(v.y); o[2] = f2bf(v.z); o[3] = f2bf(v.w);
  *(u16x4*)(V + i) = o;
}

// ---------------------------------------------------------------------------
// S-GEMM: S[b][q][k] = sum_h Q[q][h]*K[k][h]  (3-term split-bf16).
// Round-4 structure (4 tensors staged per K-step, 8 steps, 48 MFMA/step)
// + source-swizzled staging (0 bank conflicts). Epilogue: per-64-key-block
// stats + P=bf16(exp(s-m)) via swizzled LDS bounce. Grid XCD-chunk swizzled.
// ---------------------------------------------------------------------------
__global__ __launch_bounds__(256, 2) void sgemm_kernel(
    const ushort_t* __restrict__ Qh, const ushort_t* __restrict__ Ql,
    const ushort_t* __restrict__ Kh, const ushort_t* __restrict__ Kl,
    ushort_t* __restrict__ Pbuf, float* __restrict__ mpart,
    float* __restrict__ lpart, int bbase) {
  // ---- XCD bijective chunk swizzle (grid 18x18x4 = 1296, %8 == 0) ----
  const int lin = blockIdx.x + 18 * blockIdx.y + 324 * blockIdx.z;
  const int o = (lin & 7) * 162 + (lin >> 3);
  const int b = o / 324;           // batch within group
  const int rem = o % 324;
  const int q0 = (rem % 18) * 128;
  const int k0 = (rem / 18) * 128;

  const int gb = bbase + b;
  const int tid = threadIdx.x;
  const int lane = tid & 63;
  const int w = tid >> 6;
  const int l15 = lane & 15;
  const int quad = lane >> 4;
  const int wm = w & 1;
  const int wn = w >> 1;

  // [buf][tensor 0=Qh 1=Ql 2=Kh 3=Kl][row][col]  (64 KB)
  __shared__ __align__(16) ushort_t AB[2][4][128][32];

  f32x4 acc[4][4] = {};

  const ushort_t* srcs[4] = {Qh + ((size_t)gb * PP + q0) * HIDD,
                             Ql + ((size_t)gb * PP + q0) * HIDD,
                             Kh + ((size_t)gb * PP + k0) * HIDD,
                             Kl + ((size_t)gb * PP + k0) * HIDD};
  const ushort_t* mysrc = srcs[w];
  const int r16 = lane >> 2;       // row-in-16-group
  const int c4 = lane & 3;         // 16B chunk
  const int swz = c4 ^ ((r16 >> 1) & 3);  // source chunk swizzle

  // wave w stages tensor w: 8 async16 per kstep (source-swizzled)
  auto stage = [&](int cs, int buf) {
    const ushort_t* sp = mysrc + cs * 32 + swz * 8;
#pragma unroll
    for (int i = 0; i < 8; ++i)
      async16(sp + (size_t)(i * 16 + r16) * HIDD, &AB[buf][w][i * 16][0]);
  };

  stage(0, 0);
  __syncthreads();

  for (int cs = 0; cs < 8; ++cs) {
    const int buf = cs & 1;
    if (cs + 1 < 8) stage(cs + 1, buf ^ 1);

    bf16x8 ah[4], al[4], bh[4], bl[4];
#pragma unroll
    for (int mt = 0; mt < 4; ++mt) {
      const int row = wm * 64 + mt * 16 + l15;
      const int g = (quad ^ ((row >> 1) & 3)) * 8;
      ah[mt] = load_bf8(&AB[buf][0][row][g]);
      al[mt] = load_bf8(&AB[buf][1][row][g]);
    }
#pragma unroll
    for (int nt = 0; nt < 4; ++nt) {
      const int row = wn * 64 + nt * 16 + l15;
      const int g = (quad ^ ((row >> 1) & 3)) * 8;
      bh[nt] = load_bf8(&AB[buf][2][row][g]);
      bl[nt] = load_bf8(&AB[buf][3][row][g]);
    }
#pragma unroll
    for (int mt = 0; mt < 4; ++mt)
#pragma unroll
      for (int nt = 0; nt < 4; ++nt) {
        acc[mt][nt] = MFMA16(ah[mt], bh[nt], acc[mt][nt]);
        acc[mt][nt] = MFMA16(al[mt], bh[nt], acc[mt][nt]);
        acc[mt][nt] = MFMA16(ah[mt], bl[nt], acc[mt][nt]);
      }
    __syncthreads();
  }

  // ---- epilogue: per-row 64-key-block max -> P=exp(s-m) bf16 + stats ----
  ushort_t* Pt = (ushort_t*)&AB[0][0][0][0];  // [128][128] hw, chunk-swizzled
  const int kb = (k0 >> 6) + wn;
#pragma unroll
  for (int mt = 0; mt < 4; ++mt) {
#pragma unroll
    for (int r = 0; r < 4; ++r) {
      float m = fmaxf(fmaxf(acc[mt][0][r], acc[mt][1][r]),
                      fmaxf(acc[mt][2][r], acc[mt][3][r]));
      m = fmaxf(m, __shfl_xor(m, 1));
      m = fmaxf(m, __shfl_xor(m, 2));
      m = fmaxf(m, __shfl_xor(m, 4));
      m = fmaxf(m, __shfl_xor(m, 8));
      float p0 = __expf(acc[mt][0][r] - m);
      float p1 = __expf(acc[mt][1][r] - m);
      float p2 = __expf(acc[mt][2][r] - m);
      float p3 = __expf(acc[mt][3][r] - m);
      float e = p0 + p1 + p2 + p3;
      e += __shfl_xor(e, 1);
      e += __shfl_xor(e, 2);
      e += __shfl_xor(e, 4);
      e += __shfl_xor(e, 8);
      const int row = wm * 64 + mt * 16 + quad * 4 + r;
      const int rx = row & 15;
      ushort_t* ptrow = Pt + row * 128;
      float pv[4] = {p0, p1, p2, p3};
#pragma unroll
      for (int nt = 0; nt < 4; ++nt) {
        const int col = wn * 64 + nt * 16 + l15;
        ptrow[(((col >> 3) ^ rx) << 3) + (col & 7)] = f2bf(pv[nt]);
      }
      if (l15 == 0) {
        const int q = q0 + row;
        mpart[((size_t)b * NKB + kb) * PP + q] = m;
        lpart[((size_t)b * NKB + kb) * PP + q] = e;
      }
    }
  }
  __syncthreads();
  {
    const int row = tid >> 1;
    const int half2 = tid & 1;
    const int rx = row & 15;
    const ushort_t* srcr = Pt + row * 128;
    ushort_t* dst = Pbuf + ((size_t)b * PP + q0 + row) * PP + k0 + half2 * 64;
#pragma unroll
    for (int j = 0; j < 8; ++j) {
      u16x8 v = *(const u16x8*)(srcr + (((half2 * 8 + j) ^ rx) << 3));
      *(u16x8*)(dst + j * 8) = v;
    }
  }
}

// ---------------------------------------------------------------------------
// Stats reduce: alpha[b][kb][q] = exp(m_kb - M) / L
// ---------------------------------------------------------------------------
__global__ __launch_bounds__(256) void stats_kernel(
    const float* __restrict__ mpart, const float* __restrict__ lpart,
    float* __restrict__ alphab) {
  const int q = blockIdx.x * 256 + threadIdx.x;
  const int b = blockIdx.y;
  float m[NKB];
  float M = -3.0e38f;
#pragma unroll
  for (int kb = 0; kb < NKB; ++kb) {
    m[kb] = mpart[((size_t)b * NKB + kb) * PP + q];
    M = fmaxf(M, m[kb]);
  }
  float L = 0.f;
#pragma unroll
  for (int kb = 0; kb < NKB; ++kb)
    L += __expf(m[kb] - M) * lpart[((size_t)b * NKB + kb) * PP + q];
  const float rL = 1.f / L;
#pragma unroll
  for (int kb = 0; kb < NKB; ++kb)
    alphab[((size_t)b * NKB + kb) * PP + q] = __expf(m[kb] - M) * rL;
}

// ---------------------------------------------------------------------------
// PV-GEMM: out[gb][c][q] = sum_kb alpha[q][kb] * sum_{k in kb} P[q][k]*V[c][k]
// Pure bf16 MFMA inner loop. Grid XCD-chunk swizzled; 3 blocks/CU.
// ---------------------------------------------------------------------------
__global__ __launch_bounds__(256, 3) void pv_kernel(
    const ushort_t* __restrict__ Pb, const ushort_t* __restrict__ Vb,
    const float* __restrict__ alphab, float* __restrict__ out, int bbase) {
  // ---- XCD bijective chunk swizzle (grid 36x4x4 = 576, %8 == 0) ----
  const int lin = blockIdx.x + 36 * blockIdx.y + 144 * blockIdx.z;
  const int o = (lin & 7) * 72 + (lin >> 3);
  const int b = o / 144;
  const int m0 = (o % 36) * 64;          // q
  const int n0 = ((o / 36) % 4) * 128;   // channel

  const int gb = bbase + b;
  const int tid = threadIdx.x;
  const int lane = tid & 63;
  const int w = tid >> 6;
  const int l15 = lane & 15;
  const int quad = lane >> 4;
  const int wm = w & 1;
  const int wn = w >> 1;

  __shared__ __align__(16) ushort_t Plds[2][64][64];  // 16 KB
  __shared__ __align__(16) ushort_t Vt[2][128][64];   // 32 KB

  f32x4 acc[2][4] = {};

  const ushort_t* P_base = Pb + ((size_t)b * PP + m0) * PP;
  const ushort_t* V_base = Vb + ((size_t)gb * CRD + n0) * PP;
  const float* a_base =
      alphab + (size_t)b * NKB * PP + m0 + wm * 32 + quad * 4;

  const int lr = lane >> 3;  // row-in-8-group
  const int lc = lane & 7;   // 16B chunk 0..7

  auto stage = [&](int kb, int buf) {
#pragma unroll
    for (int j = 0; j < 2; ++j) {
      const int row = w * 16 + j * 8 + lr;
      const int ch = lc ^ (row & 7);
      async16(P_base + (size_t)row * PP + kb * 64 + ch * 8,
              &Plds[buf][w * 16 + j * 8][0]);
    }
#pragma unroll
    for (int j = 0; j < 4; ++j) {
      const int row = w * 32 + j * 8 + lr;
      const int ch = lc ^ (row & 7);
      async16(V_base + (size_t)row * PP + kb * 64 + ch * 8,
              &Vt[buf][w * 32 + j * 8][0]);
    }
  };

  stage(0, 0);
  __syncthreads();

  for (int kb = 0; kb < NKB; ++kb) {
    const int buf = kb & 1;
    if (kb + 1 < NKB) stage(kb + 1, buf ^ 1);

    f32x4 av[2];
#pragma unroll
    for (int mt = 0; mt < 2; ++mt)
      av[mt] = *(const f32x4*)(a_base + (size_t)kb * PP + mt * 16);

    f32x4 pacc[2][4] = {};
#pragma unroll
    for (int h = 0; h < 2; ++h) {
      bf16x8 pa[2], vf[4];
#pragma unroll
      for (int mt = 0; mt < 2; ++mt) {
        const int row = wm * 32 + mt * 16 + l15;
        const int g = (h * 4 + quad) ^ (row & 7);
        pa[mt] = load_bf8(&Plds[buf][row][g * 8]);
      }
#pragma unroll
      for (int nt = 0; nt < 4; ++nt) {
        const int row = wn * 64 + nt * 16 + l15;
        const int g = (h * 4 + quad) ^ (row & 7);
        vf[nt] = load_bf8(&Vt[buf][row][g * 8]);
      }
#pragma unroll
      for (int mt = 0; mt < 2; ++mt)
#pragma unroll
        for (int nt = 0; nt < 4; ++nt)
          pacc[mt][nt] = MFMA16(pa[mt], vf[nt], pacc[mt][nt]);
    }

#pragma unroll
    for (int mt = 0; mt < 2; ++mt)
#pragma unroll
      for (int nt = 0; nt < 4; ++nt)
        acc[mt][nt] += av[mt] * pacc[mt][nt];

    __syncthreads();
  }

  // epilogue: alpha already includes 1/L. out[gb][c][q].
#pragma unroll
  for (int mt = 0; mt < 2; ++mt) {
    const int q = m0 + wm * 32 + mt * 16 + quad * 4;
#pragma unroll
    for (int nt = 0; nt < 4; ++nt) {
      const int ch = n0 + wn * 64 + nt * 16 + l15;
      *(f32x4*)(out + ((size_t)gb * CRD + ch) * PP + q) = acc[mt][nt];
    }
  }
}

// ---------------------------------------------------------------------------
// Fallback fused attention for small workspaces.
// ---------------------------------------------------------------------------
__global__ __launch_bounds__(256, 2) void attn_direct_kernel(
    const ushort_t* __restrict__ Qh, const ushort_t* __restrict__ Ql,
    const ushort_t* __restrict__ Kh, const ushort_t* __restrict__ Kl,
    const ushort_t* __restrict__ Vb, float* __restrict__ out) {
  const int b = blockIdx.z;
  const int qb = blockIdx.x;
  const int tid = threadIdx.x;
  const int lane = tid & 63;
  const int w = tid >> 6;
  const int l15 = lane & 15;
  const int quad = lane >> 4;

  __shared__ __align__(16) ushort_t Kbuf[2][2][16][520];
  __shared__ __align__(16) ushort_t P_lds[4][16][40];

  bf16x8 qh[8], ql[8];
  {
    const size_t qrow = ((size_t)b * PP + qb * 64 + w * 16 + l15) * HIDD;
#pragma unroll
    for (int ks = 0; ks < 8; ++ks) {
      qh[ks] = load_bf8(Qh + qrow + ks * 32 + quad * 8);
      ql[ks] = load_bf8(Ql + qrow + ks * 32 + quad * 8);
    }
  }

  f32x4 o_acc[32] = {};
  float m_run[4] = {-3.0e38f, -3.0e38f, -3.0e38f, -3.0e38f};
  float l_run[4] = {0.f, 0.f, 0.f, 0.f};

  const ushort_t* Kb[2] = {Kh + (size_t)b * PP * HIDD,
                           Kl + (size_t)b * PP * HIDD};
  const ushort_t* vbase = Vb + ((size_t)b * CRD + l15) * PP + quad * 8;

  auto stage = [&](int t, int buf) {
#pragma unroll
    for (int j = 0; j < 8; ++j) {
      const int idx = w * 8 + j;
      const int hl = idx >> 4;
      const int pair = idx & 15;
      const ushort_t* src =
          Kb[hl] + ((size_t)(t * 32 + pair * 2)) * HIDD + lane * 8;
      async16(src, &Kbuf[buf][hl][pair][0]);
    }
  };

  stage(0, 0);
  __syncthreads();

  for (int t = 0; t < PP / 32; ++t) {
    const int buf = t & 1;
    if (t + 1 < PP / 32) stage(t + 1, buf ^ 1);

    f32x4 sa0 = {}, sa1 = {};
#pragma unroll
    for (int ks = 0; ks < 8; ++ks) {
      const int co = (l15 & 1) * 256 + ks * 32 + quad * 8;
      bf16x8 kh0 = load_bf8(&Kbuf[buf][0][(l15 >> 1)][co]);
      bf16x8 kl0 = load_bf8(&Kbuf[buf][1][(l15 >> 1)][co]);
      bf16x8 kh1 = load_bf8(&Kbuf[buf][0][8 + (l15 >> 1)][co]);
      bf16x8 kl1 = load_bf8(&Kbuf[buf][1][8 + (l15 >> 1)][co]);
      sa0 = MFMA16(qh[ks], kh0, sa0);
      sa1 = MFMA16(qh[ks], kh1, sa1);
      sa0 = MFMA16(ql[ks], kh0, sa0);
      sa1 = MFMA16(ql[ks], kh1, sa1);
      sa0 = MFMA16(qh[ks], kl0, sa0);
      sa1 = MFMA16(qh[ks], kl1, sa1);
    }

    float mx[4], al[4], p0[4], p1[4], rs[4];
#pragma unroll
    for (int r = 0; r < 4; ++r) mx[r] = fmaxf(sa0[r], sa1[r]);
#pragma unroll
    for (int d = 1; d < 16; d <<= 1)
#pragma unroll
      for (int r = 0; r < 4; ++r) mx[r] = fmaxf(mx[r], __shfl_xor(mx[r], d));
#pragma unroll
    for (int r = 0; r < 4; ++r) {
      const float mnew = fmaxf(m_run[r], mx[r]);
      al[r] = __expf(m_run[r] - mnew);
      m_run[r] = mnew;
      p0[r] = __expf(sa0[r] - mnew);
      p1[r] = __expf(sa1[r] - mnew);
      rs[r] = p0[r] + p1[r];
    }
#pragma unroll
    for (int d = 1; d < 16; d <<= 1)
#pragma unroll
      for (int r = 0; r < 4; ++r) rs[r] += __shfl_xor(rs[r], d);
#pragma unroll
    for (int r = 0; r < 4; ++r) l_run[r] = l_run[r] * al[r] + rs[r];

#pragma unroll
    for (int r = 0; r < 4; ++r) {
      P_lds[w][quad * 4 + r][l15] = f2bf(p0[r]);
      P_lds[w][quad * 4 + r][16 + l15] = f2bf(p1[r]);
    }
    asm volatile("s_waitcnt lgkmcnt(0)" ::: "memory");
    bf16x8 pa = load_bf8(&P_lds[w][l15][quad * 8]);

#pragma unroll
    for (int nt = 0; nt < 32; ++nt)
#pragma unroll
      for (int r = 0; r < 4; ++r) o_acc[nt][r] *= al[r];

    const ushort_t* vt = vbase + t * 32;
#pragma unroll
    for (int nt = 0; nt < 32; ++nt) {
      bf16x8 vfr = load_bf8(vt + (size_t)nt * 16 * PP);
      o_acc[nt] = MFMA16(pa, vfr, o_acc[nt]);
    }
    __syncthreads();
  }

  float rl[4];
#pragma unroll
  for (int r = 0; r < 4; ++r) rl[r] = 1.f / l_run[r];
  const int q0 = qb * 64 + w * 16 + quad * 4;
#pragma unroll
  for (int nt = 0; nt < 32; ++nt) {
    const int c = nt * 16 + l15;
    float* op = out + ((size_t)b * CRD + c) * PP + q0;
#pragma unroll
    for (int r = 0; r < 4; ++r) op[r] = o_acc[nt][r] * rl[r];
  }
}

// ---------------------------------------------------------------------------
extern "C" void kernel_launch(void* const* d_in, const int* in_sizes, int n_in,
                              void* d_out, int out_size, void* d_ws,
                              size_t ws_size, hipStream_t stream) {
  (void)in_sizes; (void)n_in; (void)out_size;

  const float* Xq = (const float*)d_in[0];
  const float* Xr = (const float*)d_in[1];
  const float* Wq = (const float*)d_in[2];
  const float* bq = (const float*)d_in[3];
  const float* Wk = (const float*)d_in[4];
  const float* bk = (const float*)d_in[5];
  float* out = (float*)d_out;

  const size_t nQK = (size_t)BB * PP * HIDD;  // 4.72M elems
  const size_t nV = (size_t)BB * CRD * PP;    // 9.44M elems

  ushort_t* p = (ushort_t*)d_ws;
  ushort_t* Qh = p; p += nQK;
  ushort_t* Ql = p; p += nQK;
  ushort_t* Kh = p; p += nQK;
  ushort_t* Kl = p; p += nQK;
  ushort_t* Vb = p; p += nV;
  ushort_t* scratch = p;

  // attn view of scratch:
  ushort_t* Pbuf = scratch;                               // GB*PP*PP u16 = 42.5 MB
  float* mpart = (float*)(Pbuf + (size_t)GB * PP * PP);   // GB*NKB*PP f32
  float* lpart = mpart + (size_t)GB * NKB * PP;
  float* alphab = lpart + (size_t)GB * NKB * PP;
  char* attn_end = (char*)(alphab + (size_t)GB * NKB * PP);

  // proj view of scratch (transient, used before attn phase):
  ushort_t* Xth = scratch;
  ushort_t* Xtl = Xth + (size_t)BB * PP * CQD;
  ushort_t* Wh2 = Xtl + (size_t)BB * PP * CQD;
  ushort_t* Wl2 = Wh2 + (size_t)HIDD * CQD;
  char* proj_end = (char*)(Wl2 + (size_t)HIDD * CQD);

  char* endp = proj_end > attn_end ? proj_end : attn_end;
  const size_t needed = (size_t)(endp - (char*)d_ws);

  if (ws_size >= needed) {
    wcast_kernel<<<dim3(HIDD * CQD / 2048), 256, 0, stream>>>(Wq, Wh2, Wl2);
    tcast_kernel<CQD, false><<<dim3(PP / 64, CQD / 64, BB), 256, 0, stream>>>(
        Xq, Xth, Xtl, nullptr);
    projgemm_kernel<CQD><<<dim3(BB * PP / 128, HIDD / 64), 256, 0, stream>>>(
        Wh2, Wl2, Xth, Xtl, bq, Qh, Ql);

    wcast_kernel<<<dim3(HIDD * CRD / 2048), 256, 0, stream>>>(Wk, Wh2, Wl2);
    tcast_kernel<CRD, true><<<dim3(PP / 64, CRD / 64, BB), 256, 0, stream>>>(
        Xr, Xth, Xtl, Vb);
    projgemm_kernel<CRD><<<dim3(BB * PP / 128, HIDD / 64), 256, 0, stream>>>(
        Wh2, Wl2, Xth, Xtl, bk, Kh, Kl);

    for (int g = 0; g < BB / GB; ++g) {
      const int bbase = g * GB;
      sgemm_kernel<<<dim3(PP / 128, PP / 128, GB), 256, 0, stream>>>(
          Qh, Ql, Kh, Kl, Pbuf, mpart, lpart, bbase);
      stats_kernel<<<dim3(PP / 256, GB), 256, 0, stream>>>(mpart, lpart,
                                                           alphab);
      pv_kernel<<<dim3(PP / 64, CRD / 128, GB), 256, 0, stream>>>(
          Pbuf, Vb, alphab, out, bbase);
    }
  } else {
    proj_kernel<CQD><<<dim3(4, PP / 64, BB), 256, 0, stream>>>(Xq, Wq, bq, Qh,
                                                               Ql);
    proj_kernel<CRD><<<dim3(4, PP / 64, BB), 256, 0, stream>>>(Xr, Wk, bk, Kh,
                                                               Kl);
    cast_v_kernel<<<dim3(nV / 1024), 256, 0, stream>>>(Xr, Vb);
    attn_direct_kernel<<<dim3(PP / 64, 1, BB), 256, 0, stream>>>(
        Qh, Ql, Kh, Kl, Vb, out);
  }
}

// Round 8
// 479.009 us; speedup vs baseline: 1.0467x; 1.0467x over previous
//
#include <hip/hip_runtime.h>

// (B, CQ, CR, HID, H, W) = (8, 1024, 512, 256, 48, 48)
#define BB   8
#define PP   2304
#define CQD  1024
#define CRD  512
#define HIDD 256
#define GB   4       // batches per group (P scratch reuse)
#define NKB  36      // 64-key stat blocks per row
#define LOG2E 1.4426950408889634f

typedef float f32x4 __attribute__((ext_vector_type(4)));
typedef __bf16 bf16x8 __attribute__((ext_vector_type(8)));
typedef unsigned short u16x8 __attribute__((ext_vector_type(8)));
typedef unsigned short u16x4 __attribute__((ext_vector_type(4)));
typedef unsigned int u32x4 __attribute__((ext_vector_type(4)));
typedef unsigned short ushort_t;

__device__ __forceinline__ unsigned short f2bf(float f) {
  unsigned int u = __float_as_uint(f);
  u += 0x7fffu + ((u >> 16) & 1u);  // RNE
  return (unsigned short)(u >> 16);
}
__device__ __forceinline__ float bf2f(unsigned short h) {
  return __uint_as_float(((unsigned int)h) << 16);
}
__device__ __forceinline__ bf16x8 load_bf8(const ushort_t* p) {
  return *(const bf16x8*)p;
}
__device__ __forceinline__ void async16(const void* g, void* l) {
  __builtin_amdgcn_global_load_lds(
      (const __attribute__((address_space(1))) unsigned int*)g,
      (__attribute__((address_space(3))) unsigned int*)l, 16, 0, 0);
}

#define MFMA16(a, b, c) __builtin_amdgcn_mfma_f32_16x16x32_bf16((a), (b), (c), 0, 0, 0)

// ---------------------------------------------------------------------------
// W cast: W[o][c] f32 -> split bf16 Wh/Wl (same layout). One-shot.
// ---------------------------------------------------------------------------
__global__ __launch_bounds__(256) void wcast_kernel(
    const float* __restrict__ W, ushort_t* __restrict__ Wh,
    ushort_t* __restrict__ Wl) {
  const size_t i = ((size_t)blockIdx.x * 256 + threadIdx.x) * 8;
  float4 a = *(const float4*)(W + i);
  float4 b2 = *(const float4*)(W + i + 4);
  float av[8] = {a.x, a.y, a.z, a.w, b2.x, b2.y, b2.z, b2.w};
  u16x8 h, l;
#pragma unroll
  for (int j = 0; j < 8; ++j) {
    unsigned short hh = f2bf(av[j]);
    h[j] = hh;
    l[j] = f2bf(av[j] - bf2f(hh));
  }
  *(u16x8*)(Wh + i) = h;
  *(u16x8*)(Wl + i) = l;
}

// ---------------------------------------------------------------------------
// X transpose-cast: X[b][c][p] f32 -> Xth/Xtl[b*P+p][c] split bf16.
// WV: additionally emit V[b][c][p] = bf16(X) (fuses old cast_v read).
// ---------------------------------------------------------------------------
template <int C, bool WV>
__global__ __launch_bounds__(256) void tcast_kernel(
    const float* __restrict__ X, ushort_t* __restrict__ Th,
    ushort_t* __restrict__ Tl, ushort_t* __restrict__ Vb) {
  const int b = blockIdx.z;
  const int p0 = blockIdx.x * 64;
  const int c0 = blockIdx.y * 64;
  const int tid = threadIdx.x;

  __shared__ unsigned int HL[64][66];  // [p_local][c_local] = h | l<<16

  {
    const int cr = tid >> 2;  // c row 0..63
    const int ch = tid & 3;   // p chunk of 16
    const float* src = X + ((size_t)b * C + c0 + cr) * PP + p0 + ch * 16;
    u16x8 vcast[2];
#pragma unroll
    for (int i = 0; i < 4; ++i) {
      float4 v = *(const float4*)(src + i * 4);
      float vv[4] = {v.x, v.y, v.z, v.w};
#pragma unroll
      for (int k = 0; k < 4; ++k) {
        unsigned short h = f2bf(vv[k]);
        unsigned short l = f2bf(vv[k] - bf2f(h));
        HL[ch * 16 + i * 4 + k][cr] =
            (unsigned int)h | ((unsigned int)l << 16);
        if (WV) vcast[i >> 1][(i & 1) * 4 + k] = h;
      }
    }
    if (WV) {
      ushort_t* vd = Vb + ((size_t)b * C + c0 + cr) * PP + p0 + ch * 16;
      *(u16x8*)(vd) = vcast[0];
      *(u16x8*)(vd + 8) = vcast[1];
    }
  }
  __syncthreads();
  {
    const int pr = tid >> 2;  // p row 0..63
    const int pc = tid & 3;   // c chunk of 16
    u16x8 hv[2], lv[2];
#pragma unroll
    for (int m = 0; m < 2; ++m)
#pragma unroll
      for (int j = 0; j < 8; ++j) {
        unsigned int wb = HL[pr][pc * 16 + m * 8 + j];
        hv[m][j] = (unsigned short)(wb & 0xffffu);
        lv[m][j] = (unsigned short)(wb >> 16);
      }
    const size_t obase = ((size_t)b * PP + p0 + pr) * C + c0 + pc * 16;
    *(u16x8*)(Th + obase) = hv[0];
    *(u16x8*)(Th + obase + 8) = hv[1];
    *(u16x8*)(Tl + obase) = lv[0];
    *(u16x8*)(Tl + obase + 8) = lv[1];
  }
}

// ---------------------------------------------------------------------------
// Projection GEMM: Out[bp][o] = sum_c W[o][c] X[bp][c], 3-term split-bf16.
// Tile 128bp x 64o, grid 576. o-INNER XCD ordering: the 4 o-tiles of each
// bp-tile are adjacent in dispatch order on the same XCD -> X panel is
// fetched from HBM once and L2-served 3x (round-7 FETCH showed 2x X
// over-fetch with o-outer ordering). Source-swizzled staging.
// ---------------------------------------------------------------------------
template <int C>
__global__ __launch_bounds__(256, 3) void projgemm_kernel(
    const ushort_t* __restrict__ Wh, const ushort_t* __restrict__ Wl,
    const ushort_t* __restrict__ Xh, const ushort_t* __restrict__ Xl,
    const float* __restrict__ bias, ushort_t* __restrict__ Oh,
    ushort_t* __restrict__ Ol) {
  // grid 144 x 4 = 576 = 8 XCD x 72; chunk j: bp = j>>2 (18 per XCD), o = j&3
  const int lin = blockIdx.x + 144 * blockIdx.y;
  const int xcd = lin & 7;
  const int j = lin >> 3;  // [0,72)
  const int bp0 = (xcd * 18 + (j >> 2)) * 128;
  const int o0 = (j & 3) * 64;

  const int tid = threadIdx.x;
  const int lane = tid & 63;
  const int w = tid >> 6;
  const int l15 = lane & 15;
  const int quad = lane >> 4;
  const int wm = w & 1;   // o half (2 x 32)
  const int wn = w >> 1;  // bp half (2 x 64)

  __shared__ __align__(16) ushort_t Wt[2][2][64][32];   // 16 KB
  __shared__ __align__(16) ushort_t Xt[2][2][128][32];  // 32 KB

  f32x4 acc[2][4] = {};

  const ushort_t* Wb[2] = {Wh + (size_t)o0 * C, Wl + (size_t)o0 * C};
  const ushort_t* Xb[2] = {Xh + (size_t)bp0 * C, Xl + (size_t)bp0 * C};

  const int r16 = lane >> 2;
  const int c4 = lane & 3;
  const int swz = c4 ^ ((r16 >> 1) & 3);  // source chunk swizzle

  // 24 staging regions of 16 rows: 0-7 = W (2 tensors x 4), 8-23 = X (2 x 8).
  auto stage = [&](int cs, int buf) {
    const int ko = cs * 32;
#pragma unroll
    for (int j2 = 0; j2 < 6; ++j2) {
      const int reg = w * 6 + j2;
      if (reg < 8) {
        const int t = reg >> 2, rg = reg & 3;
        async16(Wb[t] + (size_t)(rg * 16 + r16) * C + ko + swz * 8,
                &Wt[buf][t][rg * 16][0]);
      } else {
        const int t = (reg - 8) >> 3, rg = (reg - 8) & 7;
        async16(Xb[t] + (size_t)(rg * 16 + r16) * C + ko + swz * 8,
                &Xt[buf][t][rg * 16][0]);
      }
    }
  };

  stage(0, 0);
  __syncthreads();

  const int NS = C / 32;
  for (int cs = 0; cs < NS; ++cs) {
    const int buf = cs & 1;
    if (cs + 1 < NS) stage(cs + 1, buf ^ 1);

    bf16x8 ah[2], al[2], bh[4], bl[4];
#pragma unroll
    for (int mt = 0; mt < 2; ++mt) {
      const int row = wm * 32 + mt * 16 + l15;
      const int g = (quad ^ ((row >> 1) & 3)) * 8;
      ah[mt] = load_bf8(&Wt[buf][0][row][g]);
      al[mt] = load_bf8(&Wt[buf][1][row][g]);
    }
#pragma unroll
    for (int nt = 0; nt < 4; ++nt) {
      const int row = wn * 64 + nt * 16 + l15;
      const int g = (quad ^ ((row >> 1) & 3)) * 8;
      bh[nt] = load_bf8(&Xt[buf][0][row][g]);
      bl[nt] = load_bf8(&Xt[buf][1][row][g]);
    }
#pragma unroll
    for (int mt = 0; mt < 2; ++mt)
#pragma unroll
      for (int nt = 0; nt < 4; ++nt) {
        acc[mt][nt] = MFMA16(ah[mt], bh[nt], acc[mt][nt]);
        acc[mt][nt] = MFMA16(al[mt], bh[nt], acc[mt][nt]);
        acc[mt][nt] = MFMA16(ah[mt], bl[nt], acc[mt][nt]);
      }
    __syncthreads();
  }

  // epilogue: bias + split-cast, store Oh/Ol at [bp][o]
#pragma unroll
  for (int mt = 0; mt < 2; ++mt) {
    const int ob = o0 + wm * 32 + mt * 16 + quad * 4;
    float bv[4];
#pragma unroll
    for (int r = 0; r < 4; ++r) bv[r] = bias[ob + r];
#pragma unroll
    for (int nt = 0; nt < 4; ++nt) {
      const int bp = bp0 + wn * 64 + nt * 16 + l15;
      u16x4 hs, ls;
#pragma unroll
      for (int r = 0; r < 4; ++r) {
        float v2 = acc[mt][nt][r] + bv[r];
        unsigned short h = f2bf(v2);
        hs[r] = h;
        ls[r] = f2bf(v2 - bf2f(h));
      }
      const size_t base = (size_t)bp * HIDD + ob;
      *(u16x4*)(Oh + base) = hs;
      *(u16x4*)(Ol + base) = ls;
    }
  }
}

// ---------------------------------------------------------------------------
// Old projection (kept ONLY for the small-workspace fallback path).
// ---------------------------------------------------------------------------
template <int C>
__global__ __launch_bounds__(256) void proj_kernel(
    const float* __restrict__ X, const float* __restrict__ W,
    const float* __restrict__ bias, ushort_t* __restrict__ Oh,
    ushort_t* __restrict__ Ol) {
  const int b = blockIdx.z;
  const int p0 = blockIdx.y * 64;
  const int o0 = blockIdx.x * 64;
  const int tid = threadIdx.x;
  const int lane = tid & 63;
  const int wave = tid >> 6;
  const int wm = wave & 1;
  const int wn = wave >> 1;
  const int l15 = lane & 15;
  const int quad = lane >> 4;

  __shared__ ushort_t Xh[64][40];
  __shared__ ushort_t Xl[64][40];

  f32x4 acc[2][2] = {};
  const float* Xb = X + (size_t)b * C * PP;
  const int cc = tid >> 3;
  const int ppo = (tid & 7) * 8;

  for (int c0 = 0; c0 < C; c0 += 32) {
    const float* src = Xb + (size_t)(c0 + cc) * PP + p0 + ppo;
    float4 v0 = *(const float4*)(src);
    float4 v1 = *(const float4*)(src + 4);
    float vv[8] = {v0.x, v0.y, v0.z, v0.w, v1.x, v1.y, v1.z, v1.w};
#pragma unroll
    for (int j = 0; j < 8; ++j) {
      unsigned short h = f2bf(vv[j]);
      Xh[ppo + j][cc] = h;
      Xl[ppo + j][cc] = f2bf(vv[j] - bf2f(h));
    }
    __syncthreads();

    bf16x8 wh[2], wl[2];
#pragma unroll
    for (int mt = 0; mt < 2; ++mt) {
      const float* wsrc =
          W + (size_t)(o0 + wm * 32 + mt * 16 + l15) * C + c0 + quad * 8;
      float4 a0 = *(const float4*)(wsrc);
      float4 a1 = *(const float4*)(wsrc + 4);
      float av[8] = {a0.x, a0.y, a0.z, a0.w, a1.x, a1.y, a1.z, a1.w};
      u16x8 hh, ll;
#pragma unroll
      for (int j = 0; j < 8; ++j) {
        unsigned short h = f2bf(av[j]);
        hh[j] = h;
        ll[j] = f2bf(av[j] - bf2f(h));
      }
      wh[mt] = __builtin_bit_cast(bf16x8, hh);
      wl[mt] = __builtin_bit_cast(bf16x8, ll);
    }

#pragma unroll
    for (int nt = 0; nt < 2; ++nt) {
      const int pr = wn * 32 + nt * 16 + l15;
      bf16x8 xh = load_bf8(&Xh[pr][quad * 8]);
      bf16x8 xl = load_bf8(&Xl[pr][quad * 8]);
#pragma unroll
      for (int mt = 0; mt < 2; ++mt) {
        acc[mt][nt] = MFMA16(wh[mt], xh, acc[mt][nt]);
        acc[mt][nt] = MFMA16(wl[mt], xh, acc[mt][nt]);
        acc[mt][nt] = MFMA16(wh[mt], xl, acc[mt][nt]);
      }
    }
    __syncthreads();
  }

#pragma unroll
  for (int mt = 0; mt < 2; ++mt) {
    const int ob = o0 + wm * 32 + mt * 16 + quad * 4;
#pragma unroll
    for (int nt = 0; nt < 2; ++nt) {
      const int p = p0 + wn * 32 + nt * 16 + l15;
      u16x4 hs, ls;
#pragma unroll
      for (int r = 0; r < 4; ++r) {
        float v = acc[mt][nt][r] + bias[ob + r];
        unsigned short h = f2bf(v);
        hs[r] = h;
        ls[r] = f2bf(v - bf2f(h));
      }
      const size_t base = ((size_t)b * PP + p) * HIDD + ob;
      *(u16x4*)(Oh + base) = hs;
      *(u16x4*)(Ol + base) = ls;
    }
  }
}

__global__ void cast_v_kernel(const float* __restrict__ X,
                              ushort_t* __restrict__ V) {
  const size_t i = ((size_t)blockIdx.x * 256 + threadIdx.x) * 4;
  float4 v = *(const float4*)(X + i);
  u16x4 o;
  o[0] = f2bf(v.x); o[1] = f2bf(v.y); o[2] = f2bf(v.z); o[3] = f2bf(v.w);
  *(u16x4*)(V + i) = o;
}

// ---------------------------------------------------------------------------
// S-GEMM: S[b][q][k] = sum_h Q[q][h]*K[k][h]  (3-term split-bf16).
// Round-4 structure (4 tensors staged per K-step, 8 steps, 48 MFMA/step)
// + source-swizzled staging (0 bank conflicts). Epilogue: per-64-key-block
// stats + P=bf16(exp(s-m)) via swizzled LDS bounce. Grid XCD-chunk swizzled.
// ---------------------------------------------------------------------------
__global__ __launch_bounds__(256, 2) void sgemm_kernel(
    const ushort_t* __restrict__ Qh, const ushort_t* __restrict__ Ql,
    const ushort_t* __restrict__ Kh, const ushort_t* __restrict__ Kl,
    ushort_t* __restrict__ Pbuf, float* __restrict__ mpart,
    float* __restrict__ lpart, int bbase) {
  // ---- XCD bijective chunk swizzle (grid 18x18x4 = 1296, %8 == 0) ----
  const int lin = blockIdx.x + 18 * blockIdx.y + 324 * blockIdx.z;
  const int o = (lin & 7) * 162 + (lin >> 3);
  const int b = o / 324;           // batch within group
  const int rem = o % 324;
  const int q0 = (rem % 18) * 128;
  const int k0 = (rem / 18) * 128;

  const int gb = bbase + b;
  const int tid = threadIdx.x;
  const int lane = tid & 63;
  const int w = tid >> 6;
  const int l15 = lane & 15;
  const int quad = lane >> 4;
  const int wm = w & 1;
  const int wn = w >> 1;

  // [buf][tensor 0=Qh 1=Ql 2=Kh 3=Kl][row][col]  (64 KB)
  __shared__ __align__(16) ushort_t AB[2][4][128][32];

  f32x4 acc[4][4] = {};

  const ushort_t* srcs[4] = {Qh + ((size_t)gb * PP + q0) * HIDD,
                             Ql + ((size_t)gb * PP + q0) * HIDD,
                             Kh + ((size_t)gb * PP + k0) * HIDD,
                             Kl + ((size_t)gb * PP + k0) * HIDD};
  const ushort_t* mysrc = srcs[w];
  const int r16 = lane >> 2;       // row-in-16-group
  const int c4 = lane & 3;         // 16B chunk
  const int swz = c4 ^ ((r16 >> 1) & 3);  // source chunk swizzle

  // wave w stages tensor w: 8 async16 per kstep (source-swizzled)
  auto stage = [&](int cs, int buf) {
    const ushort_t* sp = mysrc + cs * 32 + swz * 8;
#pragma unroll
    for (int i = 0; i < 8; ++i)
      async16(sp + (size_t)(i * 16 + r16) * HIDD, &AB[buf][w][i * 16][0]);
  };

  stage(0, 0);
  __syncthreads();

  for (int cs = 0; cs < 8; ++cs) {
    const int buf = cs & 1;
    if (cs + 1 < 8) stage(cs + 1, buf ^ 1);

    bf16x8 ah[4], al[4], bh[4], bl[4];
#pragma unroll
    for (int mt = 0; mt < 4; ++mt) {
      const int row = wm * 64 + mt * 16 + l15;
      const int g = (quad ^ ((row >> 1) & 3)) * 8;
      ah[mt] = load_bf8(&AB[buf][0][row][g]);
      al[mt] = load_bf8(&AB[buf][1][row][g]);
    }
#pragma unroll
    for (int nt = 0; nt < 4; ++nt) {
      const int row = wn * 64 + nt * 16 + l15;
      const int g = (quad ^ ((row >> 1) & 3)) * 8;
      bh[nt] = load_bf8(&AB[buf][2][row][g]);
      bl[nt] = load_bf8(&AB[buf][3][row][g]);
    }
#pragma unroll
    for (int mt = 0; mt < 4; ++mt)
#pragma unroll
      for (int nt = 0; nt < 4; ++nt) {
        acc[mt][nt] = MFMA16(ah[mt], bh[nt], acc[mt][nt]);
        acc[mt][nt] = MFMA16(al[mt], bh[nt], acc[mt][nt]);
        acc[mt][nt] = MFMA16(ah[mt], bl[nt], acc[mt][nt]);
      }
    __syncthreads();
  }

  // ---- epilogue: per-row 64-key-block max -> P=exp(s-m) bf16 + stats ----
  ushort_t* Pt = (ushort_t*)&AB[0][0][0][0];  // [128][128] hw, chunk-swizzled
  const int kb = (k0 >> 6) + wn;
#pragma unroll
  for (int mt = 0; mt < 4; ++mt) {
#pragma unroll
    for (int r = 0; r < 4; ++r) {
      float m = fmaxf(fmaxf(acc[mt][0][r], acc[mt][1][r]),
                      fmaxf(acc[mt][2][r], acc[mt][3][r]));
      m = fmaxf(m, __shfl_xor(m, 1));
      m = fmaxf(m, __shfl_xor(m, 2));
      m = fmaxf(m, __shfl_xor(m, 4));
      m = fmaxf(m, __shfl_xor(m, 8));
      float p0 = __expf(acc[mt][0][r] - m);
      float p1 = __expf(acc[mt][1][r] - m);
      float p2 = __expf(acc[mt][2][r] - m);
      float p3 = __expf(acc[mt][3][r] - m);
      float e = p0 + p1 + p2 + p3;
      e += __shfl_xor(e, 1);
      e += __shfl_xor(e, 2);
      e += __shfl_xor(e, 4);
      e += __shfl_xor(e, 8);
      const int row = wm * 64 + mt * 16 + quad * 4 + r;
      const int rx = row & 15;
      ushort_t* ptrow = Pt + row * 128;
      float pv[4] = {p0, p1, p2, p3};
#pragma unroll
      for (int nt = 0; nt < 4; ++nt) {
        const int col = wn * 64 + nt * 16 + l15;
        ptrow[(((col >> 3) ^ rx) << 3) + (col & 7)] = f2bf(pv[nt]);
      }
      if (l15 == 0) {
        const int q = q0 + row;
        mpart[((size_t)b * NKB + kb) * PP + q] = m;
        lpart[((size_t)b * NKB + kb) * PP + q] = e;
      }
    }
  }
  __syncthreads();
  {
    const int row = tid >> 1;
    const int half2 = tid & 1;
    const int rx = row & 15;
    const ushort_t* srcr = Pt + row * 128;
    ushort_t* dst = Pbuf + ((size_t)b * PP + q0 + row) * PP + k0 + half2 * 64;
#pragma unroll
    for (int j = 0; j < 8; ++j) {
      u16x8 v = *(const u16x8*)(srcr + (((half2 * 8 + j) ^ rx) << 3));
      *(u16x8*)(dst + j * 8) = v;
    }
  }
}

// ---------------------------------------------------------------------------
// Stats reduce: alpha[b][kb][q] = exp(m_kb - M) / L
// ---------------------------------------------------------------------------
__global__ __launch_bounds__(256) void stats_kernel(
    const float* __restrict__ mpart, const float* __restrict__ lpart,
    float* __restrict__ alphab) {
  const int q = blockIdx.x * 256 + threadIdx.x;
  const int b = blockIdx.y;
  float m[NKB];
  float M = -3.0e38f;
#pragma unroll
  for (int kb = 0; kb < NKB; ++kb) {
    m[kb] = mpart[((size_t)b * NKB + kb) * PP + q];
    M = fmaxf(M, m[kb]);
  }
  float L = 0.f;
#pragma unroll
  for (int kb = 0; kb < NKB; ++kb)
    L += __expf(m[kb] - M) * lpart[((size_t)b * NKB + kb) * PP + q];
  const float rL = 1.f / L;
#pragma unroll
  for (int kb = 0; kb < NKB; ++kb)
    alphab[((size_t)b * NKB + kb) * PP + q] = __expf(m[kb] - M) * rL;
}

// ---------------------------------------------------------------------------
// PV-GEMM: out[gb][c][q] = sum_kb alpha[q][kb] * sum_{k in kb} P[q][k]*V[c][k]
// Pure bf16 MFMA inner loop. Grid XCD-chunk swizzled; 3 blocks/CU.
// ---------------------------------------------------------------------------
__global__ __launch_bounds__(256, 3) void pv_kernel(
    const ushort_t* __restrict__ Pb, const ushort_t* __restrict__ Vb,
    const float* __restrict__ alphab, float* __restrict__ out, int bbase) {
  // ---- XCD bijective chunk swizzle (grid 36x4x4 = 576, %8 == 0) ----
  const int lin = blockIdx.x + 36 * blockIdx.y + 144 * blockIdx.z;
  const int o = (lin & 7) * 72 + (lin >> 3);
  const int b = o / 144;
  const int m0 = (o % 36) * 64;          // q
  const int n0 = ((o / 36) % 4) * 128;   // channel

  const int gb = bbase + b;
  const int tid = threadIdx.x;
  const int lane = tid & 63;
  const int w = tid >> 6;
  const int l15 = lane & 15;
  const int quad = lane >> 4;
  const int wm = w & 1;
  const int wn = w >> 1;

  __shared__ __align__(16) ushort_t Plds[2][64][64];  // 16 KB
  __shared__ __align__(16) ushort_t Vt[2][128][64];   // 32 KB

  f32x4 acc[2][4] = {};

  const ushort_t* P_base = Pb + ((size_t)b * PP + m0) * PP;
  const ushort_t* V_base = Vb + ((size_t)gb * CRD + n0) * PP;
  const float* a_base =
      alphab + (size_t)b * NKB * PP + m0 + wm * 32 + quad * 4;

  const int lr = lane >> 3;  // row-in-8-group
  const int lc = lane & 7;   // 16B chunk 0..7

  auto stage = [&](int kb, int buf) {
#pragma unroll
    for (int j = 0; j < 2; ++j) {
      const int row = w * 16 + j * 8 + lr;
      const int ch = lc ^ (row & 7);
      async16(P_base + (size_t)row * PP + kb * 64 + ch * 8,
              &Plds[buf][w * 16 + j * 8][0]);
    }
#pragma unroll
    for (int j = 0; j < 4; ++j) {
      const int row = w * 32 + j * 8 + lr;
      const int ch = lc ^ (row & 7);
      async16(V_base + (size_t)row * PP + kb * 64 + ch * 8,
              &Vt[buf][w * 32 + j * 8][0]);
    }
  };

  stage(0, 0);
  __syncthreads();

  for (int kb = 0; kb < NKB; ++kb) {
    const int buf = kb & 1;
    if (kb + 1 < NKB) stage(kb + 1, buf ^ 1);

    f32x4 av[2];
#pragma unroll
    for (int mt = 0; mt < 2; ++mt)
      av[mt] = *(const f32x4*)(a_base + (size_t)kb * PP + mt * 16);

    f32x4 pacc[2][4] = {};
#pragma unroll
    for (int h = 0; h < 2; ++h) {
      bf16x8 pa[2], vf[4];
#pragma unroll
      for (int mt = 0; mt < 2; ++mt) {
        const int row = wm * 32 + mt * 16 + l15;
        const int g = (h * 4 + quad) ^ (row & 7);
        pa[mt] = load_bf8(&Plds[buf][row][g * 8]);
      }
#pragma unroll
      for (int nt = 0; nt < 4; ++nt) {
        const int row = wn * 64 + nt * 16 + l15;
        const int g = (h * 4 + quad) ^ (row & 7);
        vf[nt] = load_bf8(&Vt[buf][row][g * 8]);
      }
#pragma unroll
      for (int mt = 0; mt < 2; ++mt)
#pragma unroll
        for (int nt = 0; nt < 4; ++nt)
          pacc[mt][nt] = MFMA16(pa[mt], vf[nt], pacc[mt][nt]);
    }

#pragma unroll
    for (int mt = 0; mt < 2; ++mt)
#pragma unroll
      for (int nt = 0; nt < 4; ++nt)
        acc[mt][nt] += av[mt] * pacc[mt][nt];

    __syncthreads();
  }

  // epilogue: alpha already includes 1/L. out[gb][c][q].
#pragma unroll
  for (int mt = 0; mt < 2; ++mt) {
    const int q = m0 + wm * 32 + mt * 16 + quad * 4;
#pragma unroll
    for (int nt = 0; nt < 4; ++nt) {
      const int ch = n0 + wn * 64 + nt * 16 + l15;
      *(f32x4*)(out + ((size_t)gb * CRD + ch) * PP + q) = acc[mt][nt];
    }
  }
}

// ---------------------------------------------------------------------------
// Fallback fused attention for small workspaces.
// ---------------------------------------------------------------------------
__global__ __launch_bounds__(256, 2) void attn_direct_kernel(
    const ushort_t* __restrict__ Qh, const ushort_t* __restrict__ Ql,
    const ushort_t* __restrict__ Kh, const ushort_t* __restrict__ Kl,
    const ushort_t* __restrict__ Vb, float* __restrict__ out) {
  const int b = blockIdx.z;
  const int qb = blockIdx.x;
  const int tid = threadIdx.x;
  const int lane = tid & 63;
  const int w = tid >> 6;
  const int l15 = lane & 15;
  const int quad = lane >> 4;

  __shared__ __align__(16) ushort_t Kbuf[2][2][16][520];
  __shared__ __align__(16) ushort_t P_lds[4][16][40];

  bf16x8 qh[8], ql[8];
  {
    const size_t qrow = ((size_t)b * PP + qb * 64 + w * 16 + l15) * HIDD;
#pragma unroll
    for (int ks = 0; ks < 8; ++ks) {
      qh[ks] = load_bf8(Qh + qrow + ks * 32 + quad * 8);
      ql[ks] = load_bf8(Ql + qrow + ks * 32 + quad * 8);
    }
  }

  f32x4 o_acc[32] = {};
  float m_run[4] = {-3.0e38f, -3.0e38f, -3.0e38f, -3.0e38f};
  float l_run[4] = {0.f, 0.f, 0.f, 0.f};

  const ushort_t* Kb[2] = {Kh + (size_t)b * PP * HIDD,
                           Kl + (size_t)b * PP * HIDD};
  const ushort_t* vbase = Vb + ((size_t)b * CRD + l15) * PP + quad * 8;

  auto stage = [&](int t, int buf) {
#pragma unroll
    for (int j = 0; j < 8; ++j) {
      const int idx = w * 8 + j;
      const int hl = idx >> 4;
      const int pair = idx & 15;
      const ushort_t* src =
          Kb[hl] + ((size_t)(t * 32 + pair * 2)) * HIDD + lane * 8;
      async16(src, &Kbuf[buf][hl][pair][0]);
    }
  };

  stage(0, 0);
  __syncthreads();

  for (int t = 0; t < PP / 32; ++t) {
    const int buf = t & 1;
    if (t + 1 < PP / 32) stage(t + 1, buf ^ 1);

    f32x4 sa0 = {}, sa1 = {};
#pragma unroll
    for (int ks = 0; ks < 8; ++ks) {
      const int co = (l15 & 1) * 256 + ks * 32 + quad * 8;
      bf16x8 kh0 = load_bf8(&Kbuf[buf][0][(l15 >> 1)][co]);
      bf16x8 kl0 = load_bf8(&Kbuf[buf][1][(l15 >> 1)][co]);
      bf16x8 kh1 = load_bf8(&Kbuf[buf][0][8 + (l15 >> 1)][co]);
      bf16x8 kl1 = load_bf8(&Kbuf[buf][1][8 + (l15 >> 1)][co]);
      sa0 = MFMA16(qh[ks], kh0, sa0);
      sa1 = MFMA16(qh[ks], kh1, sa1);
      sa0 = MFMA16(ql[ks], kh0, sa0);
      sa1 = MFMA16(ql[ks], kh1, sa1);
      sa0 = MFMA16(qh[ks], kl0, sa0);
      sa1 = MFMA16(qh[ks], kl1, sa1);
    }

    float mx[4], al[4], p0[4], p1[4], rs[4];
#pragma unroll
    for (int r = 0; r < 4; ++r) mx[r] = fmaxf(sa0[r], sa1[r]);
#pragma unroll
    for (int d = 1; d < 16; d <<= 1)
#pragma unroll
      for (int r = 0; r < 4; ++r) mx[r] = fmaxf(mx[r], __shfl_xor(mx[r], d));
#pragma unroll
    for (int r = 0; r < 4; ++r) {
      const float mnew = fmaxf(m_run[r], mx[r]);
      al[r] = __expf(m_run[r] - mnew);
      m_run[r] = mnew;
      p0[r] = __expf(sa0[r] - mnew);
      p1[r] = __expf(sa1[r] - mnew);
      rs[r] = p0[r] + p1[r];
    }
#pragma unroll
    for (int d = 1; d < 16; d <<= 1)
#pragma unroll
      for (int r = 0; r < 4; ++r) rs[r] += __shfl_xor(rs[r], d);
#pragma unroll
    for (int r = 0; r < 4; ++r) l_run[r] = l_run[r] * al[r] + rs[r];

#pragma unroll
    for (int r = 0; r < 4; ++r) {
      P_lds[w][quad * 4 + r][l15] = f2bf(p0[r]);
      P_lds[w][quad * 4 + r][16 + l15] = f2bf(p1[r]);
    }
    asm volatile("s_waitcnt lgkmcnt(0)" ::: "memory");
    bf16x8 pa = load_bf8(&P_lds[w][l15][quad * 8]);

#pragma unroll
    for (int nt = 0; nt < 32; ++nt)
#pragma unroll
      for (int r = 0; r < 4; ++r) o_acc[nt][r] *= al[r];

    const ushort_t* vt = vbase + t * 32;
#pragma unroll
    for (int nt = 0; nt < 32; ++nt) {
      bf16x8 vfr = load_bf8(vt + (size_t)nt * 16 * PP);
      o_acc[nt] = MFMA16(pa, vfr, o_acc[nt]);
    }
    __syncthreads();
  }

  float rl[4];
#pragma unroll
  for (int r = 0; r < 4; ++r) rl[r] = 1.f / l_run[r];
  const int q0 = qb * 64 + w * 16 + quad * 4;
#pragma unroll
  for (int nt = 0; nt < 32; ++nt) {
    const int c = nt * 16 + l15;
    float* op = out + ((size_t)b * CRD + c) * PP + q0;
#pragma unroll
    for (int r = 0; r < 4; ++r) op[r] = o_acc[nt][r] * rl[r];
  }
}

// ---------------------------------------------------------------------------
extern "C" void kernel_launch(void* const* d_in, const int* in_sizes, int n_in,
                              void* d_out, int out_size, void* d_ws,
                              size_t ws_size, hipStream_t stream) {
  (void)in_sizes; (void)n_in; (void)out_size;

  const float* Xq = (const float*)d_in[0];
  const float* Xr = (const float*)d_in[1];
  const float* Wq = (const float*)d_in[2];
  const float* bq = (const float*)d_in[3];
  const float* Wk = (const float*)d_in[4];
  const float* bk = (const float*)d_in[5];
  float* out = (float*)d_out;

  const size_t nQK = (size_t)BB * PP * HIDD;  // 4.72M elems
  const size_t nV = (size_t)BB * CRD * PP;    // 9.44M elems

  ushort_t* p = (ushort_t*)d_ws;
  ushort_t* Qh = p; p += nQK;
  ushort_t* Ql = p; p += nQK;
  ushort_t* Kh = p; p += nQK;
  ushort_t* Kl = p; p += nQK;
  ushort_t* Vb = p; p += nV;
  ushort_t* scratch = p;

  // attn view of scratch:
  ushort_t* Pbuf = scratch;                               // GB*PP*PP u16 = 42.5 MB
  float* mpart = (float*)(Pbuf + (size_t)GB * PP * PP);   // GB*NKB*PP f32
  float* lpart = mpart + (size_t)GB * NKB * PP;
  float* alphab = lpart + (size_t)GB * NKB * PP;
  char* attn_end = (char*)(alphab + (size_t)GB * NKB * PP);

  // proj view of scratch (transient, used before attn phase):
  ushort_t* Xth = scratch;
  ushort_t* Xtl = Xth + (size_t)BB * PP * CQD;
  ushort_t* Wh2 = Xtl + (size_t)BB * PP * CQD;
  ushort_t* Wl2 = Wh2 + (size_t)HIDD * CQD;
  char* proj_end = (char*)(Wl2 + (size_t)HIDD * CQD);

  char* endp = proj_end > attn_end ? proj_end : attn_end;
  const size_t needed = (size_t)(endp - (char*)d_ws);

  if (ws_size >= needed) {
    wcast_kernel<<<dim3(HIDD * CQD / 2048), 256, 0, stream>>>(Wq, Wh2, Wl2);
    tcast_kernel<CQD, false><<<dim3(PP / 64, CQD / 64, BB), 256, 0, stream>>>(
        Xq, Xth, Xtl, nullptr);
    projgemm_kernel<CQD><<<dim3(BB * PP / 128, HIDD / 64), 256, 0, stream>>>(
        Wh2, Wl2, Xth, Xtl, bq, Qh, Ql);

    wcast_kernel<<<dim3(HIDD * CRD / 2048), 256, 0, stream>>>(Wk, Wh2, Wl2);
    tcast_kernel<CRD, true><<<dim3(PP / 64, CRD / 64, BB), 256, 0, stream>>>(
        Xr, Xth, Xtl, Vb);
    projgemm_kernel<CRD><<<dim3(BB * PP / 128, HIDD / 64), 256, 0, stream>>>(
        Wh2, Wl2, Xth, Xtl, bk, Kh, Kl);

    for (int g = 0; g < BB / GB; ++g) {
      const int bbase = g * GB;
      sgemm_kernel<<<dim3(PP / 128, PP / 128, GB), 256, 0, stream>>>(
          Qh, Ql, Kh, Kl, Pbuf, mpart, lpart, bbase);
      stats_kernel<<<dim3(PP / 256, GB), 256, 0, stream>>>(mpart, lpart,
                                                           alphab);
      pv_kernel<<<dim3(PP / 64, CRD / 128, GB), 256, 0, stream>>>(
          Pbuf, Vb, alphab, out, bbase);
    }
  } else {
    proj_kernel<CQD><<<dim3(4, PP / 64, BB), 256, 0, stream>>>(Xq, Wq, bq, Qh,
                                                               Ql);
    proj_kernel<CRD><<<dim3(4, PP / 64, BB), 256, 0, stream>>>(Xr, Wk, bk, Kh,
                                                               Kl);
    cast_v_kernel<<<dim3(nV / 1024), 256, 0, stream>>>(Xr, Vb);
    attn_direct_kernel<<<dim3(PP / 64, 1, BB), 256, 0, stream>>>(
        Qh, Ql, Kh, Kl, Vb, out);
  }
}

// Round 9
// 470.427 us; speedup vs baseline: 1.0658x; 1.0182x over previous
//
#include <hip/hip_runtime.h>

// (B, CQ, CR, HID, H, W) = (8, 1024, 512, 256, 48, 48)
#define BB   8
#define PP   2304
#define CQD  1024
#define CRD  512
#define HIDD 256
#define GB   4       // batches per group (P scratch reuse)
#define NKB  36      // 64-key stat blocks per row
#define LOG2E 1.4426950408889634f

typedef float f32x4 __attribute__((ext_vector_type(4)));
typedef __bf16 bf16x8 __attribute__((ext_vector_type(8)));
typedef unsigned short u16x8 __attribute__((ext_vector_type(8)));
typedef unsigned short u16x4 __attribute__((ext_vector_type(4)));
typedef unsigned int u32x4 __attribute__((ext_vector_type(4)));
typedef unsigned short ushort_t;

__device__ __forceinline__ unsigned short f2bf(float f) {
  unsigned int u = __float_as_uint(f);
  u += 0x7fffu + ((u >> 16) & 1u);  // RNE
  return (unsigned short)(u >> 16);
}
__device__ __forceinline__ float bf2f(unsigned short h) {
  return __uint_as_float(((unsigned int)h) << 16);
}
__device__ __forceinline__ bf16x8 load_bf8(const ushort_t* p) {
  return *(const bf16x8*)p;
}
__device__ __forceinline__ void async16(const void* g, void* l) {
  __builtin_amdgcn_global_load_lds(
      (const __attribute__((address_space(1))) unsigned int*)g,
      (__attribute__((address_space(3))) unsigned int*)l, 16, 0, 0);
}

#define MFMA16(a, b, c) __builtin_amdgcn_mfma_f32_16x16x32_bf16((a), (b), (c), 0, 0, 0)

// ---------------------------------------------------------------------------
// W cast: W[o][c] f32 -> split bf16 Wh/Wl (same layout). One-shot.
// ---------------------------------------------------------------------------
__global__ __launch_bounds__(256) void wcast_kernel(
    const float* __restrict__ W, ushort_t* __restrict__ Wh,
    ushort_t* __restrict__ Wl) {
  const size_t i = ((size_t)blockIdx.x * 256 + threadIdx.x) * 8;
  float4 a = *(const float4*)(W + i);
  float4 b2 = *(const float4*)(W + i + 4);
  float av[8] = {a.x, a.y, a.z, a.w, b2.x, b2.y, b2.z, b2.w};
  u16x8 h, l;
#pragma unroll
  for (int j = 0; j < 8; ++j) {
    unsigned short hh = f2bf(av[j]);
    h[j] = hh;
    l[j] = f2bf(av[j] - bf2f(hh));
  }
  *(u16x8*)(Wh + i) = h;
  *(u16x8*)(Wl + i) = l;
}

// ---------------------------------------------------------------------------
// X transpose-cast: X[b][c][p] f32 -> Xth/Xtl[b*P+p][c] split bf16.
// WV: additionally emit V[b][c][p] = bf16(X) (fuses old cast_v read).
// ---------------------------------------------------------------------------
template <int C, bool WV>
__global__ __launch_bounds__(256) void tcast_kernel(
    const float* __restrict__ X, ushort_t* __restrict__ Th,
    ushort_t* __restrict__ Tl, ushort_t* __restrict__ Vb) {
  const int b = blockIdx.z;
  const int p0 = blockIdx.x * 64;
  const int c0 = blockIdx.y * 64;
  const int tid = threadIdx.x;

  __shared__ unsigned int HL[64][66];  // [p_local][c_local] = h | l<<16

  {
    const int cr = tid >> 2;  // c row 0..63
    const int ch = tid & 3;   // p chunk of 16
    const float* src = X + ((size_t)b * C + c0 + cr) * PP + p0 + ch * 16;
    u16x8 vcast[2];
#pragma unroll
    for (int i = 0; i < 4; ++i) {
      float4 v = *(const float4*)(src + i * 4);
      float vv[4] = {v.x, v.y, v.z, v.w};
#pragma unroll
      for (int k = 0; k < 4; ++k) {
        unsigned short h = f2bf(vv[k]);
        unsigned short l = f2bf(vv[k] - bf2f(h));
        HL[ch * 16 + i * 4 + k][cr] =
            (unsigned int)h | ((unsigned int)l << 16);
        if (WV) vcast[i >> 1][(i & 1) * 4 + k] = h;
      }
    }
    if (WV) {
      ushort_t* vd = Vb + ((size_t)b * C + c0 + cr) * PP + p0 + ch * 16;
      *(u16x8*)(vd) = vcast[0];
      *(u16x8*)(vd + 8) = vcast[1];
    }
  }
  __syncthreads();
  {
    const int pr = tid >> 2;  // p row 0..63
    const int pc = tid & 3;   // c chunk of 16
    u16x8 hv[2], lv[2];
#pragma unroll
    for (int m = 0; m < 2; ++m)
#pragma unroll
      for (int j = 0; j < 8; ++j) {
        unsigned int wb = HL[pr][pc * 16 + m * 8 + j];
        hv[m][j] = (unsigned short)(wb & 0xffffu);
        lv[m][j] = (unsigned short)(wb >> 16);
      }
    const size_t obase = ((size_t)b * PP + p0 + pr) * C + c0 + pc * 16;
    *(u16x8*)(Th + obase) = hv[0];
    *(u16x8*)(Th + obase + 8) = hv[1];
    *(u16x8*)(Tl + obase) = lv[0];
    *(u16x8*)(Tl + obase + 8) = lv[1];
  }
}

// ---------------------------------------------------------------------------
// Projection GEMM: Out[bp][o] = sum_c W[o][c] X[bp][c], 3-term split-bf16.
// Tile 128bp x 64o, grid 576. o-INNER XCD ordering (round-8 win: X panel
// fetched once, L2-served 3x). Source-swizzled staging.
// ---------------------------------------------------------------------------
template <int C>
__global__ __launch_bounds__(256, 3) void projgemm_kernel(
    const ushort_t* __restrict__ Wh, const ushort_t* __restrict__ Wl,
    const ushort_t* __restrict__ Xh, const ushort_t* __restrict__ Xl,
    const float* __restrict__ bias, ushort_t* __restrict__ Oh,
    ushort_t* __restrict__ Ol) {
  // grid 144 x 4 = 576 = 8 XCD x 72; chunk j: bp = j>>2 (18 per XCD), o = j&3
  const int lin = blockIdx.x + 144 * blockIdx.y;
  const int xcd = lin & 7;
  const int j = lin >> 3;  // [0,72)
  const int bp0 = (xcd * 18 + (j >> 2)) * 128;
  const int o0 = (j & 3) * 64;

  const int tid = threadIdx.x;
  const int lane = tid & 63;
  const int w = tid >> 6;
  const int l15 = lane & 15;
  const int quad = lane >> 4;
  const int wm = w & 1;   // o half (2 x 32)
  const int wn = w >> 1;  // bp half (2 x 64)

  __shared__ __align__(16) ushort_t Wt[2][2][64][32];   // 16 KB
  __shared__ __align__(16) ushort_t Xt[2][2][128][32];  // 32 KB

  f32x4 acc[2][4] = {};

  const ushort_t* Wb[2] = {Wh + (size_t)o0 * C, Wl + (size_t)o0 * C};
  const ushort_t* Xb[2] = {Xh + (size_t)bp0 * C, Xl + (size_t)bp0 * C};

  const int r16 = lane >> 2;
  const int c4 = lane & 3;
  const int swz = c4 ^ ((r16 >> 1) & 3);  // source chunk swizzle

  // 24 staging regions of 16 rows: 0-7 = W (2 tensors x 4), 8-23 = X (2 x 8).
  auto stage = [&](int cs, int buf) {
    const int ko = cs * 32;
#pragma unroll
    for (int j2 = 0; j2 < 6; ++j2) {
      const int reg = w * 6 + j2;
      if (reg < 8) {
        const int t = reg >> 2, rg = reg & 3;
        async16(Wb[t] + (size_t)(rg * 16 + r16) * C + ko + swz * 8,
                &Wt[buf][t][rg * 16][0]);
      } else {
        const int t = (reg - 8) >> 3, rg = (reg - 8) & 7;
        async16(Xb[t] + (size_t)(rg * 16 + r16) * C + ko + swz * 8,
                &Xt[buf][t][rg * 16][0]);
      }
    }
  };

  stage(0, 0);
  __syncthreads();

  const int NS = C / 32;
  for (int cs = 0; cs < NS; ++cs) {
    const int buf = cs & 1;
    if (cs + 1 < NS) stage(cs + 1, buf ^ 1);

    bf16x8 ah[2], al[2], bh[4], bl[4];
#pragma unroll
    for (int mt = 0; mt < 2; ++mt) {
      const int row = wm * 32 + mt * 16 + l15;
      const int g = (quad ^ ((row >> 1) & 3)) * 8;
      ah[mt] = load_bf8(&Wt[buf][0][row][g]);
      al[mt] = load_bf8(&Wt[buf][1][row][g]);
    }
#pragma unroll
    for (int nt = 0; nt < 4; ++nt) {
      const int row = wn * 64 + nt * 16 + l15;
      const int g = (quad ^ ((row >> 1) & 3)) * 8;
      bh[nt] = load_bf8(&Xt[buf][0][row][g]);
      bl[nt] = load_bf8(&Xt[buf][1][row][g]);
    }
#pragma unroll
    for (int mt = 0; mt < 2; ++mt)
#pragma unroll
      for (int nt = 0; nt < 4; ++nt) {
        acc[mt][nt] = MFMA16(ah[mt], bh[nt], acc[mt][nt]);
        acc[mt][nt] = MFMA16(al[mt], bh[nt], acc[mt][nt]);
        acc[mt][nt] = MFMA16(ah[mt], bl[nt], acc[mt][nt]);
      }
    __syncthreads();
  }

  // epilogue: bias + split-cast, store Oh/Ol at [bp][o]
#pragma unroll
  for (int mt = 0; mt < 2; ++mt) {
    const int ob = o0 + wm * 32 + mt * 16 + quad * 4;
    float bv[4];
#pragma unroll
    for (int r = 0; r < 4; ++r) bv[r] = bias[ob + r];
#pragma unroll
    for (int nt = 0; nt < 4; ++nt) {
      const int bp = bp0 + wn * 64 + nt * 16 + l15;
      u16x4 hs, ls;
#pragma unroll
      for (int r = 0; r < 4; ++r) {
        float v2 = acc[mt][nt][r] + bv[r];
        unsigned short h = f2bf(v2);
        hs[r] = h;
        ls[r] = f2bf(v2 - bf2f(h));
      }
      const size_t base = (size_t)bp * HIDD + ob;
      *(u16x4*)(Oh + base) = hs;
      *(u16x4*)(Ol + base) = ls;
    }
  }
}

// ---------------------------------------------------------------------------
// Old projection (kept ONLY for the small-workspace fallback path).
// ---------------------------------------------------------------------------
template <int C>
__global__ __launch_bounds__(256) void proj_kernel(
    const float* __restrict__ X, const float* __restrict__ W,
    const float* __restrict__ bias, ushort_t* __restrict__ Oh,
    ushort_t* __restrict__ Ol) {
  const int b = blockIdx.z;
  const int p0 = blockIdx.y * 64;
  const int o0 = blockIdx.x * 64;
  const int tid = threadIdx.x;
  const int lane = tid & 63;
  const int wave = tid >> 6;
  const int wm = wave & 1;
  const int wn = wave >> 1;
  const int l15 = lane & 15;
  const int quad = lane >> 4;

  __shared__ ushort_t Xh[64][40];
  __shared__ ushort_t Xl[64][40];

  f32x4 acc[2][2] = {};
  const float* Xb = X + (size_t)b * C * PP;
  const int cc = tid >> 3;
  const int ppo = (tid & 7) * 8;

  for (int c0 = 0; c0 < C; c0 += 32) {
    const float* src = Xb + (size_t)(c0 + cc) * PP + p0 + ppo;
    float4 v0 = *(const float4*)(src);
    float4 v1 = *(const float4*)(src + 4);
    float vv[8] = {v0.x, v0.y, v0.z, v0.w, v1.x, v1.y, v1.z, v1.w};
#pragma unroll
    for (int j = 0; j < 8; ++j) {
      unsigned short h = f2bf(vv[j]);
      Xh[ppo + j][cc] = h;
      Xl[ppo + j][cc] = f2bf(vv[j] - bf2f(h));
    }
    __syncthreads();

    bf16x8 wh[2], wl[2];
#pragma unroll
    for (int mt = 0; mt < 2; ++mt) {
      const float* wsrc =
          W + (size_t)(o0 + wm * 32 + mt * 16 + l15) * C + c0 + quad * 8;
      float4 a0 = *(const float4*)(wsrc);
      float4 a1 = *(const float4*)(wsrc + 4);
      float av[8] = {a0.x, a0.y, a0.z, a0.w, a1.x, a1.y, a1.z, a1.w};
      u16x8 hh, ll;
#pragma unroll
      for (int j = 0; j < 8; ++j) {
        unsigned short h = f2bf(av[j]);
        hh[j] = h;
        ll[j] = f2bf(av[j] - bf2f(h));
      }
      wh[mt] = __builtin_bit_cast(bf16x8, hh);
      wl[mt] = __builtin_bit_cast(bf16x8, ll);
    }

#pragma unroll
    for (int nt = 0; nt < 2; ++nt) {
      const int pr = wn * 32 + nt * 16 + l15;
      bf16x8 xh = load_bf8(&Xh[pr][quad * 8]);
      bf16x8 xl = load_bf8(&Xl[pr][quad * 8]);
#pragma unroll
      for (int mt = 0; mt < 2; ++mt) {
        acc[mt][nt] = MFMA16(wh[mt], xh, acc[mt][nt]);
        acc[mt][nt] = MFMA16(wl[mt], xh, acc[mt][nt]);
        acc[mt][nt] = MFMA16(wh[mt], xl, acc[mt][nt]);
      }
    }
    __syncthreads();
  }

#pragma unroll
  for (int mt = 0; mt < 2; ++mt) {
    const int ob = o0 + wm * 32 + mt * 16 + quad * 4;
#pragma unroll
    for (int nt = 0; nt < 2; ++nt) {
      const int p = p0 + wn * 32 + nt * 16 + l15;
      u16x4 hs, ls;
#pragma unroll
      for (int r = 0; r < 4; ++r) {
        float v = acc[mt][nt][r] + bias[ob + r];
        unsigned short h = f2bf(v);
        hs[r] = h;
        ls[r] = f2bf(v - bf2f(h));
      }
      const size_t base = ((size_t)b * PP + p) * HIDD + ob;
      *(u16x4*)(Oh + base) = hs;
      *(u16x4*)(Ol + base) = ls;
    }
  }
}

__global__ void cast_v_kernel(const float* __restrict__ X,
                              ushort_t* __restrict__ V) {
  const size_t i = ((size_t)blockIdx.x * 256 + threadIdx.x) * 4;
  float4 v = *(const float4*)(X + i);
  u16x4 o;
  o[0] = f2bf(v.x); o[1] = f2bf(v.y); o[2] = f2bf(v.z); o[3] = f2bf(v.w);
  *(u16x4*)(V + i) = o;
}

// ---------------------------------------------------------------------------
// S-GEMM: S[b][q][k] = sum_h Q[q][h]*K[k][h]  (3-term split-bf16).
// Round-8 structure re-partitioned over 8 waves (512 threads): wave =
// 32q x 64k sub-tile, acc[2][4]; 2 waves stage each tensor. Same tile
// (128x128), same 8 K-steps, same barrier structure, same numerics.
// 2 blocks/CU x 8 waves = 16 waves/CU (was 8) -> latency hiding.
// ---------------------------------------------------------------------------
__global__ __launch_bounds__(512, 4) void sgemm_kernel(
    const ushort_t* __restrict__ Qh, const ushort_t* __restrict__ Ql,
    const ushort_t* __restrict__ Kh, const ushort_t* __restrict__ Kl,
    ushort_t* __restrict__ Pbuf, float* __restrict__ mpart,
    float* __restrict__ lpart, int bbase) {
  // ---- XCD bijective chunk swizzle (grid 18x18x4 = 1296, %8 == 0) ----
  const int lin = blockIdx.x + 18 * blockIdx.y + 324 * blockIdx.z;
  const int o = (lin & 7) * 162 + (lin >> 3);
  const int b = o / 324;           // batch within group
  const int rem = o % 324;
  const int q0 = (rem % 18) * 128;
  const int k0 = (rem / 18) * 128;

  const int gb = bbase + b;
  const int tid = threadIdx.x;
  const int lane = tid & 63;
  const int w = tid >> 6;          // 0..7
  const int l15 = lane & 15;
  const int quad = lane >> 4;
  const int wm = w & 3;            // q band of 32 (4 bands)
  const int wn = w >> 2;           // k half of 64 (2 halves)

  // [buf][tensor 0=Qh 1=Ql 2=Kh 3=Kl][row][col]  (64 KB)
  __shared__ __align__(16) ushort_t AB[2][4][128][32];

  f32x4 acc[2][4] = {};

  const ushort_t* srcs[4] = {Qh + ((size_t)gb * PP + q0) * HIDD,
                             Ql + ((size_t)gb * PP + q0) * HIDD,
                             Kh + ((size_t)gb * PP + k0) * HIDD,
                             Kl + ((size_t)gb * PP + k0) * HIDD};
  const int st = w >> 1;           // tensor staged by this wave
  const int sh = w & 1;            // 64-row half staged
  const ushort_t* mysrc = srcs[st];
  const int r16 = lane >> 2;       // row-in-16-group
  const int c4 = lane & 3;         // 16B chunk
  const int swz = c4 ^ ((r16 >> 1) & 3);  // source chunk swizzle

  // wave w stages half sh of tensor st: 4 async16 per kstep
  auto stage = [&](int cs, int buf) {
    const ushort_t* sp = mysrc + cs * 32 + swz * 8;
#pragma unroll
    for (int i = 0; i < 4; ++i) {
      const int row = sh * 64 + i * 16;
      async16(sp + (size_t)(row + r16) * HIDD, &AB[buf][st][row][0]);
    }
  };

  stage(0, 0);
  __syncthreads();

  for (int cs = 0; cs < 8; ++cs) {
    const int buf = cs & 1;
    if (cs + 1 < 8) stage(cs + 1, buf ^ 1);

    bf16x8 ah[2], al[2], bh[4], bl[4];
#pragma unroll
    for (int mt = 0; mt < 2; ++mt) {
      const int row = wm * 32 + mt * 16 + l15;
      const int g = (quad ^ ((row >> 1) & 3)) * 8;
      ah[mt] = load_bf8(&AB[buf][0][row][g]);
      al[mt] = load_bf8(&AB[buf][1][row][g]);
    }
#pragma unroll
    for (int nt = 0; nt < 4; ++nt) {
      const int row = wn * 64 + nt * 16 + l15;
      const int g = (quad ^ ((row >> 1) & 3)) * 8;
      bh[nt] = load_bf8(&AB[buf][2][row][g]);
      bl[nt] = load_bf8(&AB[buf][3][row][g]);
    }
#pragma unroll
    for (int mt = 0; mt < 2; ++mt)
#pragma unroll
      for (int nt = 0; nt < 4; ++nt) {
        acc[mt][nt] = MFMA16(ah[mt], bh[nt], acc[mt][nt]);
        acc[mt][nt] = MFMA16(al[mt], bh[nt], acc[mt][nt]);
        acc[mt][nt] = MFMA16(ah[mt], bl[nt], acc[mt][nt]);
      }
    __syncthreads();
  }

  // ---- epilogue: per-row 64-key-block max -> P=exp(s-m) bf16 + stats ----
  ushort_t* Pt = (ushort_t*)&AB[0][0][0][0];  // [128][128] hw, chunk-swizzled
  const int kb = (k0 >> 6) + wn;
#pragma unroll
  for (int mt = 0; mt < 2; ++mt) {
#pragma unroll
    for (int r = 0; r < 4; ++r) {
      float m = fmaxf(fmaxf(acc[mt][0][r], acc[mt][1][r]),
                      fmaxf(acc[mt][2][r], acc[mt][3][r]));
      m = fmaxf(m, __shfl_xor(m, 1));
      m = fmaxf(m, __shfl_xor(m, 2));
      m = fmaxf(m, __shfl_xor(m, 4));
      m = fmaxf(m, __shfl_xor(m, 8));
      float p0 = __expf(acc[mt][0][r] - m);
      float p1 = __expf(acc[mt][1][r] - m);
      float p2 = __expf(acc[mt][2][r] - m);
      float p3 = __expf(acc[mt][3][r] - m);
      float e = p0 + p1 + p2 + p3;
      e += __shfl_xor(e, 1);
      e += __shfl_xor(e, 2);
      e += __shfl_xor(e, 4);
      e += __shfl_xor(e, 8);
      const int row = wm * 32 + mt * 16 + quad * 4 + r;
      const int rx = row & 15;
      ushort_t* ptrow = Pt + row * 128;
      float pv[4] = {p0, p1, p2, p3};
#pragma unroll
      for (int nt = 0; nt < 4; ++nt) {
        const int col = wn * 64 + nt * 16 + l15;
        ptrow[(((col >> 3) ^ rx) << 3) + (col & 7)] = f2bf(pv[nt]);
      }
      if (l15 == 0) {
        const int q = q0 + row;
        mpart[((size_t)b * NKB + kb) * PP + q] = m;
        lpart[((size_t)b * NKB + kb) * PP + q] = e;
      }
    }
  }
  __syncthreads();
  {
    const int row = tid >> 2;       // 0..127
    const int qtr = tid & 3;        // 32-col quarter
    const int rx = row & 15;
    const ushort_t* srcr = Pt + row * 128;
    ushort_t* dst = Pbuf + ((size_t)b * PP + q0 + row) * PP + k0 + qtr * 32;
#pragma unroll
    for (int j = 0; j < 4; ++j) {
      u16x8 v = *(const u16x8*)(srcr + (((qtr * 4 + j) ^ rx) << 3));
      *(u16x8*)(dst + j * 8) = v;
    }
  }
}

// ---------------------------------------------------------------------------
// Stats reduce: alpha[b][kb][q] = exp(m_kb - M) / L
// ---------------------------------------------------------------------------
__global__ __launch_bounds__(256) void stats_kernel(
    const float* __restrict__ mpart, const float* __restrict__ lpart,
    float* __restrict__ alphab) {
  const int q = blockIdx.x * 256 + threadIdx.x;
  const int b = blockIdx.y;
  float m[NKB];
  float M = -3.0e38f;
#pragma unroll
  for (int kb = 0; kb < NKB; ++kb) {
    m[kb] = mpart[((size_t)b * NKB + kb) * PP + q];
    M = fmaxf(M, m[kb]);
  }
  float L = 0.f;
#pragma unroll
  for (int kb = 0; kb < NKB; ++kb)
    L += __expf(m[kb] - M) * lpart[((size_t)b * NKB + kb) * PP + q];
  const float rL = 1.f / L;
#pragma unroll
  for (int kb = 0; kb < NKB; ++kb)
    alphab[((size_t)b * NKB + kb) * PP + q] = __expf(m[kb] - M) * rL;
}

// ---------------------------------------------------------------------------
// PV-GEMM: out[gb][c][q] = sum_kb alpha[q][kb] * sum_{k in kb} P[q][k]*V[c][k]
// Pure bf16 MFMA inner loop. Grid XCD-chunk swizzled; 3 blocks/CU.
// ---------------------------------------------------------------------------
__global__ __launch_bounds__(256, 3) void pv_kernel(
    const ushort_t* __restrict__ Pb, const ushort_t* __restrict__ Vb,
    const float* __restrict__ alphab, float* __restrict__ out, int bbase) {
  // ---- XCD bijective chunk swizzle (grid 36x4x4 = 576, %8 == 0) ----
  const int lin = blockIdx.x + 36 * blockIdx.y + 144 * blockIdx.z;
  const int o = (lin & 7) * 72 + (lin >> 3);
  const int b = o / 144;
  const int m0 = (o % 36) * 64;          // q
  const int n0 = ((o / 36) % 4) * 128;   // channel

  const int gb = bbase + b;
  const int tid = threadIdx.x;
  const int lane = tid & 63;
  const int w = tid >> 6;
  const int l15 = lane & 15;
  const int quad = lane >> 4;
  const int wm = w & 1;
  const int wn = w >> 1;

  __shared__ __align__(16) ushort_t Plds[2][64][64];  // 16 KB
  __shared__ __align__(16) ushort_t Vt[2][128][64];   // 32 KB

  f32x4 acc[2][4] = {};

  const ushort_t* P_base = Pb + ((size_t)b * PP + m0) * PP;
  const ushort_t* V_base = Vb + ((size_t)gb * CRD + n0) * PP;
  const float* a_base =
      alphab + (size_t)b * NKB * PP + m0 + wm * 32 + quad * 4;

  const int lr = lane >> 3;  // row-in-8-group
  const int lc = lane & 7;   // 16B chunk 0..7

  auto stage = [&](int kb, int buf) {
#pragma unroll
    for (int j = 0; j < 2; ++j) {
      const int row = w * 16 + j * 8 + lr;
      const int ch = lc ^ (row & 7);
      async16(P_base + (size_t)row * PP + kb * 64 + ch * 8,
              &Plds[buf][w * 16 + j * 8][0]);
    }
#pragma unroll
    for (int j = 0; j < 4; ++j) {
      const int row = w * 32 + j * 8 + lr;
      const int ch = lc ^ (row & 7);
      async16(V_base + (size_t)row * PP + kb * 64 + ch * 8,
              &Vt[buf][w * 32 + j * 8][0]);
    }
  };

  stage(0, 0);
  __syncthreads();

  for (int kb = 0; kb < NKB; ++kb) {
    const int buf = kb & 1;
    if (kb + 1 < NKB) stage(kb + 1, buf ^ 1);

    f32x4 av[2];
#pragma unroll
    for (int mt = 0; mt < 2; ++mt)
      av[mt] = *(const f32x4*)(a_base + (size_t)kb * PP + mt * 16);

    f32x4 pacc[2][4] = {};
#pragma unroll
    for (int h = 0; h < 2; ++h) {
      bf16x8 pa[2], vf[4];
#pragma unroll
      for (int mt = 0; mt < 2; ++mt) {
        const int row = wm * 32 + mt * 16 + l15;
        const int g = (h * 4 + quad) ^ (row & 7);
        pa[mt] = load_bf8(&Plds[buf][row][g * 8]);
      }
#pragma unroll
      for (int nt = 0; nt < 4; ++nt) {
        const int row = wn * 64 + nt * 16 + l15;
        const int g = (h * 4 + quad) ^ (row & 7);
        vf[nt] = load_bf8(&Vt[buf][row][g * 8]);
      }
#pragma unroll
      for (int mt = 0; mt < 2; ++mt)
#pragma unroll
        for (int nt = 0; nt < 4; ++nt)
          pacc[mt][nt] = MFMA16(pa[mt], vf[nt], pacc[mt][nt]);
    }

#pragma unroll
    for (int mt = 0; mt < 2; ++mt)
#pragma unroll
      for (int nt = 0; nt < 4; ++nt)
        acc[mt][nt] += av[mt] * pacc[mt][nt];

    __syncthreads();
  }

  // epilogue: alpha already includes 1/L. out[gb][c][q].
#pragma unroll
  for (int mt = 0; mt < 2; ++mt) {
    const int q = m0 + wm * 32 + mt * 16 + quad * 4;
#pragma unroll
    for (int nt = 0; nt < 4; ++nt) {
      const int ch = n0 + wn * 64 + nt * 16 + l15;
      *(f32x4*)(out + ((size_t)gb * CRD + ch) * PP + q) = acc[mt][nt];
    }
  }
}

// ---------------------------------------------------------------------------
// Fallback fused attention for small workspaces.
// ---------------------------------------------------------------------------
__global__ __launch_bounds__(256, 2) void attn_direct_kernel(
    const ushort_t* __restrict__ Qh, const ushort_t* __restrict__ Ql,
    const ushort_t* __restrict__ Kh, const ushort_t* __restrict__ Kl,
    const ushort_t* __restrict__ Vb, float* __restrict__ out) {
  const int b = blockIdx.z;
  const int qb = blockIdx.x;
  const int tid = threadIdx.x;
  const int lane = tid & 63;
  const int w = tid >> 6;
  const int l15 = lane & 15;
  const int quad = lane >> 4;

  __shared__ __align__(16) ushort_t Kbuf[2][2][16][520];
  __shared__ __align__(16) ushort_t P_lds[4][16][40];

  bf16x8 qh[8], ql[8];
  {
    const size_t qrow = ((size_t)b * PP + qb * 64 + w * 16 + l15) * HIDD;
#pragma unroll
    for (int ks = 0; ks < 8; ++ks) {
      qh[ks] = load_bf8(Qh + qrow + ks * 32 + quad * 8);
      ql[ks] = load_bf8(Ql + qrow + ks * 32 + quad * 8);
    }
  }

  f32x4 o_acc[32] = {};
  float m_run[4] = {-3.0e38f, -3.0e38f, -3.0e38f, -3.0e38f};
  float l_run[4] = {0.f, 0.f, 0.f, 0.f};

  const ushort_t* Kb[2] = {Kh + (size_t)b * PP * HIDD,
                           Kl + (size_t)b * PP * HIDD};
  const ushort_t* vbase = Vb + ((size_t)b * CRD + l15) * PP + quad * 8;

  auto stage = [&](int t, int buf) {
#pragma unroll
    for (int j = 0; j < 8; ++j) {
      const int idx = w * 8 + j;
      const int hl = idx >> 4;
      const int pair = idx & 15;
      const ushort_t* src =
          Kb[hl] + ((size_t)(t * 32 + pair * 2)) * HIDD + lane * 8;
      async16(src, &Kbuf[buf][hl][pair][0]);
    }
  };

  stage(0, 0);
  __syncthreads();

  for (int t = 0; t < PP / 32; ++t) {
    const int buf = t & 1;
    if (t + 1 < PP / 32) stage(t + 1, buf ^ 1);

    f32x4 sa0 = {}, sa1 = {};
#pragma unroll
    for (int ks = 0; ks < 8; ++ks) {
      const int co = (l15 & 1) * 256 + ks * 32 + quad * 8;
      bf16x8 kh0 = load_bf8(&Kbuf[buf][0][(l15 >> 1)][co]);
      bf16x8 kl0 = load_bf8(&Kbuf[buf][1][(l15 >> 1)][co]);
      bf16x8 kh1 = load_bf8(&Kbuf[buf][0][8 + (l15 >> 1)][co]);
      bf16x8 kl1 = load_bf8(&Kbuf[buf][1][8 + (l15 >> 1)][co]);
      sa0 = MFMA16(qh[ks], kh0, sa0);
      sa1 = MFMA16(qh[ks], kh1, sa1);
      sa0 = MFMA16(ql[ks], kh0, sa0);
      sa1 = MFMA16(ql[ks], kh1, sa1);
      sa0 = MFMA16(qh[ks], kl0, sa0);
      sa1 = MFMA16(qh[ks], kl1, sa1);
    }

    float mx[4], al[4], p0[4], p1[4], rs[4];
#pragma unroll
    for (int r = 0; r < 4; ++r) mx[r] = fmaxf(sa0[r], sa1[r]);
#pragma unroll
    for (int d = 1; d < 16; d <<= 1)
#pragma unroll
      for (int r = 0; r < 4; ++r) mx[r] = fmaxf(mx[r], __shfl_xor(mx[r], d));
#pragma unroll
    for (int r = 0; r < 4; ++r) {
      const float mnew = fmaxf(m_run[r], mx[r]);
      al[r] = __expf(m_run[r] - mnew);
      m_run[r] = mnew;
      p0[r] = __expf(sa0[r] - mnew);
      p1[r] = __expf(sa1[r] - mnew);
      rs[r] = p0[r] + p1[r];
    }
#pragma unroll
    for (int d = 1; d < 16; d <<= 1)
#pragma unroll
      for (int r = 0; r < 4; ++r) rs[r] += __shfl_xor(rs[r], d);
#pragma unroll
    for (int r = 0; r < 4; ++r) l_run[r] = l_run[r] * al[r] + rs[r];

#pragma unroll
    for (int r = 0; r < 4; ++r) {
      P_lds[w][quad * 4 + r][l15] = f2bf(p0[r]);
      P_lds[w][quad * 4 + r][16 + l15] = f2bf(p1[r]);
    }
    asm volatile("s_waitcnt lgkmcnt(0)" ::: "memory");
    bf16x8 pa = load_bf8(&P_lds[w][l15][quad * 8]);

#pragma unroll
    for (int nt = 0; nt < 32; ++nt)
#pragma unroll
      for (int r = 0; r < 4; ++r) o_acc[nt][r] *= al[r];

    const ushort_t* vt = vbase + t * 32;
#pragma unroll
    for (int nt = 0; nt < 32; ++nt) {
      bf16x8 vfr = load_bf8(vt + (size_t)nt * 16 * PP);
      o_acc[nt] = MFMA16(pa, vfr, o_acc[nt]);
    }
    __syncthreads();
  }

  float rl[4];
#pragma unroll
  for (int r = 0; r < 4; ++r) rl[r] = 1.f / l_run[r];
  const int q0 = qb * 64 + w * 16 + quad * 4;
#pragma unroll
  for (int nt = 0; nt < 32; ++nt) {
    const int c = nt * 16 + l15;
    float* op = out + ((size_t)b * CRD + c) * PP + q0;
#pragma unroll
    for (int r = 0; r < 4; ++r) op[r] = o_acc[nt][r] * rl[r];
  }
}

// ---------------------------------------------------------------------------
extern "C" void kernel_launch(void* const* d_in, const int* in_sizes, int n_in,
                              void* d_out, int out_size, void* d_ws,
                              size_t ws_size, hipStream_t stream) {
  (void)in_sizes; (void)n_in; (void)out_size;

  const float* Xq = (const float*)d_in[0];
  const float* Xr = (const float*)d_in[1];
  const float* Wq = (const float*)d_in[2];
  const float* bq = (const float*)d_in[3];
  const float* Wk = (const float*)d_in[4];
  const float* bk = (const float*)d_in[5];
  float* out = (float*)d_out;

  const size_t nQK = (size_t)BB * PP * HIDD;  // 4.72M elems
  const size_t nV = (size_t)BB * CRD * PP;    // 9.44M elems

  ushort_t* p = (ushort_t*)d_ws;
  ushort_t* Qh = p; p += nQK;
  ushort_t* Ql = p; p += nQK;
  ushort_t* Kh = p; p += nQK;
  ushort_t* Kl = p; p += nQK;
  ushort_t* Vb = p; p += nV;
  ushort_t* scratch = p;

  // attn view of scratch:
  ushort_t* Pbuf = scratch;                               // GB*PP*PP u16 = 42.5 MB
  float* mpart = (float*)(Pbuf + (size_t)GB * PP * PP);   // GB*NKB*PP f32
  float* lpart = mpart + (size_t)GB * NKB * PP;
  float* alphab = lpart + (size_t)GB * NKB * PP;
  char* attn_end = (char*)(alphab + (size_t)GB * NKB * PP);

  // proj view of scratch (transient, used before attn phase):
  ushort_t* Xth = scratch;
  ushort_t* Xtl = Xth + (size_t)BB * PP * CQD;
  ushort_t* Wh2 = Xtl + (size_t)BB * PP * CQD;
  ushort_t* Wl2 = Wh2 + (size_t)HIDD * CQD;
  char* proj_end = (char*)(Wl2 + (size_t)HIDD * CQD);

  char* endp = proj_end > attn_end ? proj_end : attn_end;
  const size_t needed = (size_t)(endp - (char*)d_ws);

  if (ws_size >= needed) {
    wcast_kernel<<<dim3(HIDD * CQD / 2048), 256, 0, stream>>>(Wq, Wh2, Wl2);
    tcast_kernel<CQD, false><<<dim3(PP / 64, CQD / 64, BB), 256, 0, stream>>>(
        Xq, Xth, Xtl, nullptr);
    projgemm_kernel<CQD><<<dim3(BB * PP / 128, HIDD / 64), 256, 0, stream>>>(
        Wh2, Wl2, Xth, Xtl, bq, Qh, Ql);

    wcast_kernel<<<dim3(HIDD * CRD / 2048), 256, 0, stream>>>(Wk, Wh2, Wl2);
    tcast_kernel<CRD, true><<<dim3(PP / 64, CRD / 64, BB), 256, 0, stream>>>(
        Xr, Xth, Xtl, Vb);
    projgemm_kernel<CRD><<<dim3(BB * PP / 128, HIDD / 64), 256, 0, stream>>>(
        Wh2, Wl2, Xth, Xtl, bk, Kh, Kl);

    for (int g = 0; g < BB / GB; ++g) {
      const int bbase = g * GB;
      sgemm_kernel<<<dim3(PP / 128, PP / 128, GB), 512, 0, stream>>>(
          Qh, Ql, Kh, Kl, Pbuf, mpart, lpart, bbase);
      stats_kernel<<<dim3(PP / 256, GB), 256, 0, stream>>>(mpart, lpart,
                                                           alphab);
      pv_kernel<<<dim3(PP / 64, CRD / 128, GB), 256, 0, stream>>>(
          Pbuf, Vb, alphab, out, bbase);
    }
  } else {
    proj_kernel<CQD><<<dim3(4, PP / 64, BB), 256, 0, stream>>>(Xq, Wq, bq, Qh,
                                                               Ql);
    proj_kernel<CRD><<<dim3(4, PP / 64, BB), 256, 0, stream>>>(Xr, Wk, bk, Kh,
                                                               Kl);
    cast_v_kernel<<<dim3(nV / 1024), 256, 0, stream>>>(Xr, Vb);
    attn_direct_kernel<<<dim3(PP / 64, 1, BB), 256, 0, stream>>>(
        Qh, Ql, Kh, Kl, Vb, out);
  }
}

// Round 10
// 445.102 us; speedup vs baseline: 1.1265x; 1.0569x over previous
//
#include <hip/hip_runtime.h>

// (B, CQ, CR, HID, H, W) = (8, 1024, 512, 256, 48, 48)
#define BB   8
#define PP   2304
#define CQD  1024
#define CRD  512
#define HIDD 256
#define NKB  36      // 64-key stat blocks per row
#define LOG2E 1.4426950408889634f

typedef float f32x4 __attribute__((ext_vector_type(4)));
typedef __bf16 bf16x8 __attribute__((ext_vector_type(8)));
typedef unsigned short u16x8 __attribute__((ext_vector_type(8)));
typedef unsigned short u16x4 __attribute__((ext_vector_type(4)));
typedef unsigned int u32x4 __attribute__((ext_vector_type(4)));
typedef unsigned short ushort_t;

__device__ __forceinline__ unsigned short f2bf(float f) {
  unsigned int u = __float_as_uint(f);
  u += 0x7fffu + ((u >> 16) & 1u);  // RNE
  return (unsigned short)(u >> 16);
}
__device__ __forceinline__ float bf2f(unsigned short h) {
  return __uint_as_float(((unsigned int)h) << 16);
}
__device__ __forceinline__ bf16x8 load_bf8(const ushort_t* p) {
  return *(const bf16x8*)p;
}
__device__ __forceinline__ void async16(const void* g, void* l) {
  __builtin_amdgcn_global_load_lds(
      (const __attribute__((address_space(1))) unsigned int*)g,
      (__attribute__((address_space(3))) unsigned int*)l, 16, 0, 0);
}

#define MFMA16(a, b, c) __builtin_amdgcn_mfma_f32_16x16x32_bf16((a), (b), (c), 0, 0, 0)

// ---------------------------------------------------------------------------
// W cast: W[o][c] f32 -> split bf16 Wh/Wl (same layout). One-shot.
// ---------------------------------------------------------------------------
__global__ __launch_bounds__(256) void wcast_kernel(
    const float* __restrict__ W, ushort_t* __restrict__ Wh,
    ushort_t* __restrict__ Wl) {
  const size_t i = ((size_t)blockIdx.x * 256 + threadIdx.x) * 8;
  float4 a = *(const float4*)(W + i);
  float4 b2 = *(const float4*)(W + i + 4);
  float av[8] = {a.x, a.y, a.z, a.w, b2.x, b2.y, b2.z, b2.w};
  u16x8 h, l;
#pragma unroll
  for (int j = 0; j < 8; ++j) {
    unsigned short hh = f2bf(av[j]);
    h[j] = hh;
    l[j] = f2bf(av[j] - bf2f(hh));
  }
  *(u16x8*)(Wh + i) = h;
  *(u16x8*)(Wl + i) = l;
}

// ---------------------------------------------------------------------------
// X transpose-cast: X[b][c][p] f32 -> Xth/Xtl[b*P+p][c] split bf16.
// WV: additionally emit V[b][c][p] = bf16(X) (fuses old cast_v read).
// ---------------------------------------------------------------------------
template <int C, bool WV>
__global__ __launch_bounds__(256) void tcast_kernel(
    const float* __restrict__ X, ushort_t* __restrict__ Th,
    ushort_t* __restrict__ Tl, ushort_t* __restrict__ Vb) {
  const int b = blockIdx.z;
  const int p0 = blockIdx.x * 64;
  const int c0 = blockIdx.y * 64;
  const int tid = threadIdx.x;

  __shared__ unsigned int HL[64][66];  // [p_local][c_local] = h | l<<16

  {
    const int cr = tid >> 2;  // c row 0..63
    const int ch = tid & 3;   // p chunk of 16
    const float* src = X + ((size_t)b * C + c0 + cr) * PP + p0 + ch * 16;
    u16x8 vcast[2];
#pragma unroll
    for (int i = 0; i < 4; ++i) {
      float4 v = *(const float4*)(src + i * 4);
      float vv[4] = {v.x, v.y, v.z, v.w};
#pragma unroll
      for (int k = 0; k < 4; ++k) {
        unsigned short h = f2bf(vv[k]);
        unsigned short l = f2bf(vv[k] - bf2f(h));
        HL[ch * 16 + i * 4 + k][cr] =
            (unsigned int)h | ((unsigned int)l << 16);
        if (WV) vcast[i >> 1][(i & 1) * 4 + k] = h;
      }
    }
    if (WV) {
      ushort_t* vd = Vb + ((size_t)b * C + c0 + cr) * PP + p0 + ch * 16;
      *(u16x8*)(vd) = vcast[0];
      *(u16x8*)(vd + 8) = vcast[1];
    }
  }
  __syncthreads();
  {
    const int pr = tid >> 2;  // p row 0..63
    const int pc = tid & 3;   // c chunk of 16
    u16x8 hv[2], lv[2];
#pragma unroll
    for (int m = 0; m < 2; ++m)
#pragma unroll
      for (int j = 0; j < 8; ++j) {
        unsigned int wb = HL[pr][pc * 16 + m * 8 + j];
        hv[m][j] = (unsigned short)(wb & 0xffffu);
        lv[m][j] = (unsigned short)(wb >> 16);
      }
    const size_t obase = ((size_t)b * PP + p0 + pr) * C + c0 + pc * 16;
    *(u16x8*)(Th + obase) = hv[0];
    *(u16x8*)(Th + obase + 8) = hv[1];
    *(u16x8*)(Tl + obase) = lv[0];
    *(u16x8*)(Tl + obase + 8) = lv[1];
  }
}

// ---------------------------------------------------------------------------
// Projection GEMM: Out[bp][o] = sum_c W[o][c] X[bp][c], 3-term split-bf16.
// Tile 128bp x 64o, grid 576. o-INNER XCD ordering (round-8 win: X panel
// fetched once, L2-served 3x). Source-swizzled staging.
// ---------------------------------------------------------------------------
template <int C>
__global__ __launch_bounds__(256, 3) void projgemm_kernel(
    const ushort_t* __restrict__ Wh, const ushort_t* __restrict__ Wl,
    const ushort_t* __restrict__ Xh, const ushort_t* __restrict__ Xl,
    const float* __restrict__ bias, ushort_t* __restrict__ Oh,
    ushort_t* __restrict__ Ol) {
  // grid 144 x 4 = 576 = 8 XCD x 72; chunk j: bp = j>>2 (18 per XCD), o = j&3
  const int lin = blockIdx.x + 144 * blockIdx.y;
  const int xcd = lin & 7;
  const int j = lin >> 3;  // [0,72)
  const int bp0 = (xcd * 18 + (j >> 2)) * 128;
  const int o0 = (j & 3) * 64;

  const int tid = threadIdx.x;
  const int lane = tid & 63;
  const int w = tid >> 6;
  const int l15 = lane & 15;
  const int quad = lane >> 4;
  const int wm = w & 1;   // o half (2 x 32)
  const int wn = w >> 1;  // bp half (2 x 64)

  __shared__ __align__(16) ushort_t Wt[2][2][64][32];   // 16 KB
  __shared__ __align__(16) ushort_t Xt[2][2][128][32];  // 32 KB

  f32x4 acc[2][4] = {};

  const ushort_t* Wb[2] = {Wh + (size_t)o0 * C, Wl + (size_t)o0 * C};
  const ushort_t* Xb[2] = {Xh + (size_t)bp0 * C, Xl + (size_t)bp0 * C};

  const int r16 = lane >> 2;
  const int c4 = lane & 3;
  const int swz = c4 ^ ((r16 >> 1) & 3);  // source chunk swizzle

  // 24 staging regions of 16 rows: 0-7 = W (2 tensors x 4), 8-23 = X (2 x 8).
  auto stage = [&](int cs, int buf) {
    const int ko = cs * 32;
#pragma unroll
    for (int j2 = 0; j2 < 6; ++j2) {
      const int reg = w * 6 + j2;
      if (reg < 8) {
        const int t = reg >> 2, rg = reg & 3;
        async16(Wb[t] + (size_t)(rg * 16 + r16) * C + ko + swz * 8,
                &Wt[buf][t][rg * 16][0]);
      } else {
        const int t = (reg - 8) >> 3, rg = (reg - 8) & 7;
        async16(Xb[t] + (size_t)(rg * 16 + r16) * C + ko + swz * 8,
                &Xt[buf][t][rg * 16][0]);
      }
    }
  };

  stage(0, 0);
  __syncthreads();

  const int NS = C / 32;
  for (int cs = 0; cs < NS; ++cs) {
    const int buf = cs & 1;
    if (cs + 1 < NS) stage(cs + 1, buf ^ 1);

    bf16x8 ah[2], al[2], bh[4], bl[4];
#pragma unroll
    for (int mt = 0; mt < 2; ++mt) {
      const int row = wm * 32 + mt * 16 + l15;
      const int g = (quad ^ ((row >> 1) & 3)) * 8;
      ah[mt] = load_bf8(&Wt[buf][0][row][g]);
      al[mt] = load_bf8(&Wt[buf][1][row][g]);
    }
#pragma unroll
    for (int nt = 0; nt < 4; ++nt) {
      const int row = wn * 64 + nt * 16 + l15;
      const int g = (quad ^ ((row >> 1) & 3)) * 8;
      bh[nt] = load_bf8(&Xt[buf][0][row][g]);
      bl[nt] = load_bf8(&Xt[buf][1][row][g]);
    }
#pragma unroll
    for (int mt = 0; mt < 2; ++mt)
#pragma unroll
      for (int nt = 0; nt < 4; ++nt) {
        acc[mt][nt] = MFMA16(ah[mt], bh[nt], acc[mt][nt]);
        acc[mt][nt] = MFMA16(al[mt], bh[nt], acc[mt][nt]);
        acc[mt][nt] = MFMA16(ah[mt], bl[nt], acc[mt][nt]);
      }
    __syncthreads();
  }

  // epilogue: bias + split-cast, store Oh/Ol at [bp][o]
#pragma unroll
  for (int mt = 0; mt < 2; ++mt) {
    const int ob = o0 + wm * 32 + mt * 16 + quad * 4;
    float bv[4];
#pragma unroll
    for (int r = 0; r < 4; ++r) bv[r] = bias[ob + r];
#pragma unroll
    for (int nt = 0; nt < 4; ++nt) {
      const int bp = bp0 + wn * 64 + nt * 16 + l15;
      u16x4 hs, ls;
#pragma unroll
      for (int r = 0; r < 4; ++r) {
        float v2 = acc[mt][nt][r] + bv[r];
        unsigned short h = f2bf(v2);
        hs[r] = h;
        ls[r] = f2bf(v2 - bf2f(h));
      }
      const size_t base = (size_t)bp * HIDD + ob;
      *(u16x4*)(Oh + base) = hs;
      *(u16x4*)(Ol + base) = ls;
    }
  }
}

// ---------------------------------------------------------------------------
// Old projection (kept ONLY for the small-workspace fallback path).
// ---------------------------------------------------------------------------
template <int C>
__global__ __launch_bounds__(256) void proj_kernel(
    const float* __restrict__ X, const float* __restrict__ W,
    const float* __restrict__ bias, ushort_t* __restrict__ Oh,
    ushort_t* __restrict__ Ol) {
  const int b = blockIdx.z;
  const int p0 = blockIdx.y * 64;
  const int o0 = blockIdx.x * 64;
  const int tid = threadIdx.x;
  const int lane = tid & 63;
  const int wave = tid >> 6;
  const int wm = wave & 1;
  const int wn = wave >> 1;
  const int l15 = lane & 15;
  const int quad = lane >> 4;

  __shared__ ushort_t Xh[64][40];
  __shared__ ushort_t Xl[64][40];

  f32x4 acc[2][2] = {};
  const float* Xb = X + (size_t)b * C * PP;
  const int cc = tid >> 3;
  const int ppo = (tid & 7) * 8;

  for (int c0 = 0; c0 < C; c0 += 32) {
    const float* src = Xb + (size_t)(c0 + cc) * PP + p0 + ppo;
    float4 v0 = *(const float4*)(src);
    float4 v1 = *(const float4*)(src + 4);
    float vv[8] = {v0.x, v0.y, v0.z, v0.w, v1.x, v1.y, v1.z, v1.w};
#pragma unroll
    for (int j = 0; j < 8; ++j) {
      unsigned short h = f2bf(vv[j]);
      Xh[ppo + j][cc] = h;
      Xl[ppo + j][cc] = f2bf(vv[j] - bf2f(h));
    }
    __syncthreads();

    bf16x8 wh[2], wl[2];
#pragma unroll
    for (int mt = 0; mt < 2; ++mt) {
      const float* wsrc =
          W + (size_t)(o0 + wm * 32 + mt * 16 + l15) * C + c0 + quad * 8;
      float4 a0 = *(const float4*)(wsrc);
      float4 a1 = *(const float4*)(wsrc + 4);
      float av[8] = {a0.x, a0.y, a0.z, a0.w, a1.x, a1.y, a1.z, a1.w};
      u16x8 hh, ll;
#pragma unroll
      for (int j = 0; j < 8; ++j) {
        unsigned short h = f2bf(av[j]);
        hh[j] = h;
        ll[j] = f2bf(av[j] - bf2f(h));
      }
      wh[mt] = __builtin_bit_cast(bf16x8, hh);
      wl[mt] = __builtin_bit_cast(bf16x8, ll);
    }

#pragma unroll
    for (int nt = 0; nt < 2; ++nt) {
      const int pr = wn * 32 + nt * 16 + l15;
      bf16x8 xh = load_bf8(&Xh[pr][quad * 8]);
      bf16x8 xl = load_bf8(&Xl[pr][quad * 8]);
#pragma unroll
      for (int mt = 0; mt < 2; ++mt) {
        acc[mt][nt] = MFMA16(wh[mt], xh, acc[mt][nt]);
        acc[mt][nt] = MFMA16(wl[mt], xh, acc[mt][nt]);
        acc[mt][nt] = MFMA16(wh[mt], xl, acc[mt][nt]);
      }
    }
    __syncthreads();
  }

#pragma unroll
  for (int mt = 0; mt < 2; ++mt) {
    const int ob = o0 + wm * 32 + mt * 16 + quad * 4;
#pragma unroll
    for (int nt = 0; nt < 2; ++nt) {
      const int p = p0 + wn * 32 + nt * 16 + l15;
      u16x4 hs, ls;
#pragma unroll
      for (int r = 0; r < 4; ++r) {
        float v = acc[mt][nt][r] + bias[ob + r];
        unsigned short h = f2bf(v);
        hs[r] = h;
        ls[r] = f2bf(v - bf2f(h));
      }
      const size_t base = ((size_t)b * PP + p) * HIDD + ob;
      *(u16x4*)(Oh + base) = hs;
      *(u16x4*)(Ol + base) = ls;
    }
  }
}

__global__ void cast_v_kernel(const float* __restrict__ X,
                              ushort_t* __restrict__ V) {
  const size_t i = ((size_t)blockIdx.x * 256 + threadIdx.x) * 4;
  float4 v = *(const float4*)(X + i);
  u16x4 o;
  o[0] = f2bf(v.x); o[1] = f2bf(v.y); o[2] = f2bf(v.z); o[3] = f2bf(v.w);
  *(u16x4*)(V + i) = o;
}

// ---------------------------------------------------------------------------
// S-GEMM: S[b][q][k] = sum_h Q[q][h]*K[k][h]  (3-term split-bf16).
// 512 threads, 8 waves (round-9 win). Templated on group size GBT:
// grid 18 x 18 x GBT, XCD chunk = 324*GBT/8 (each XCD owns whole batches).
// ---------------------------------------------------------------------------
template <int GBT>
__global__ __launch_bounds__(512, 4) void sgemm_kernel(
    const ushort_t* __restrict__ Qh, const ushort_t* __restrict__ Ql,
    const ushort_t* __restrict__ Kh, const ushort_t* __restrict__ Kl,
    ushort_t* __restrict__ Pbuf, float* __restrict__ mpart,
    float* __restrict__ lpart, int bbase) {
  // ---- XCD bijective chunk swizzle (grid 18*18*GBT, %8 == 0) ----
  const int lin = blockIdx.x + 18 * blockIdx.y + 324 * blockIdx.z;
  const int o = (lin & 7) * (324 * GBT / 8) + (lin >> 3);
  const int b = o / 324;           // batch within group
  const int rem = o % 324;
  const int q0 = (rem % 18) * 128;
  const int k0 = (rem / 18) * 128;

  const int gb = bbase + b;
  const int tid = threadIdx.x;
  const int lane = tid & 63;
  const int w = tid >> 6;          // 0..7
  const int l15 = lane & 15;
  const int quad = lane >> 4;
  const int wm = w & 3;            // q band of 32 (4 bands)
  const int wn = w >> 2;           // k half of 64 (2 halves)

  // [buf][tensor 0=Qh 1=Ql 2=Kh 3=Kl][row][col]  (64 KB)
  __shared__ __align__(16) ushort_t AB[2][4][128][32];

  f32x4 acc[2][4] = {};

  const ushort_t* srcs[4] = {Qh + ((size_t)gb * PP + q0) * HIDD,
                             Ql + ((size_t)gb * PP + q0) * HIDD,
                             Kh + ((size_t)gb * PP + k0) * HIDD,
                             Kl + ((size_t)gb * PP + k0) * HIDD};
  const int st = w >> 1;           // tensor staged by this wave
  const int sh = w & 1;            // 64-row half staged
  const ushort_t* mysrc = srcs[st];
  const int r16 = lane >> 2;       // row-in-16-group
  const int c4 = lane & 3;         // 16B chunk
  const int swz = c4 ^ ((r16 >> 1) & 3);  // source chunk swizzle

  // wave w stages half sh of tensor st: 4 async16 per kstep
  auto stage = [&](int cs, int buf) {
    const ushort_t* sp = mysrc + cs * 32 + swz * 8;
#pragma unroll
    for (int i = 0; i < 4; ++i) {
      const int row = sh * 64 + i * 16;
      async16(sp + (size_t)(row + r16) * HIDD, &AB[buf][st][row][0]);
    }
  };

  stage(0, 0);
  __syncthreads();

  for (int cs = 0; cs < 8; ++cs) {
    const int buf = cs & 1;
    if (cs + 1 < 8) stage(cs + 1, buf ^ 1);

    bf16x8 ah[2], al[2], bh[4], bl[4];
#pragma unroll
    for (int mt = 0; mt < 2; ++mt) {
      const int row = wm * 32 + mt * 16 + l15;
      const int g = (quad ^ ((row >> 1) & 3)) * 8;
      ah[mt] = load_bf8(&AB[buf][0][row][g]);
      al[mt] = load_bf8(&AB[buf][1][row][g]);
    }
#pragma unroll
    for (int nt = 0; nt < 4; ++nt) {
      const int row = wn * 64 + nt * 16 + l15;
      const int g = (quad ^ ((row >> 1) & 3)) * 8;
      bh[nt] = load_bf8(&AB[buf][2][row][g]);
      bl[nt] = load_bf8(&AB[buf][3][row][g]);
    }
#pragma unroll
    for (int mt = 0; mt < 2; ++mt)
#pragma unroll
      for (int nt = 0; nt < 4; ++nt) {
        acc[mt][nt] = MFMA16(ah[mt], bh[nt], acc[mt][nt]);
        acc[mt][nt] = MFMA16(al[mt], bh[nt], acc[mt][nt]);
        acc[mt][nt] = MFMA16(ah[mt], bl[nt], acc[mt][nt]);
      }
    __syncthreads();
  }

  // ---- epilogue: per-row 64-key-block max -> P=exp(s-m) bf16 + stats ----
  ushort_t* Pt = (ushort_t*)&AB[0][0][0][0];  // [128][128] hw, chunk-swizzled
  const int kb = (k0 >> 6) + wn;
#pragma unroll
  for (int mt = 0; mt < 2; ++mt) {
#pragma unroll
    for (int r = 0; r < 4; ++r) {
      float m = fmaxf(fmaxf(acc[mt][0][r], acc[mt][1][r]),
                      fmaxf(acc[mt][2][r], acc[mt][3][r]));
      m = fmaxf(m, __shfl_xor(m, 1));
      m = fmaxf(m, __shfl_xor(m, 2));
      m = fmaxf(m, __shfl_xor(m, 4));
      m = fmaxf(m, __shfl_xor(m, 8));
      float p0 = __expf(acc[mt][0][r] - m);
      float p1 = __expf(acc[mt][1][r] - m);
      float p2 = __expf(acc[mt][2][r] - m);
      float p3 = __expf(acc[mt][3][r] - m);
      float e = p0 + p1 + p2 + p3;
      e += __shfl_xor(e, 1);
      e += __shfl_xor(e, 2);
      e += __shfl_xor(e, 4);
      e += __shfl_xor(e, 8);
      const int row = wm * 32 + mt * 16 + quad * 4 + r;
      const int rx = row & 15;
      ushort_t* ptrow = Pt + row * 128;
      float pv[4] = {p0, p1, p2, p3};
#pragma unroll
      for (int nt = 0; nt < 4; ++nt) {
        const int col = wn * 64 + nt * 16 + l15;
        ptrow[(((col >> 3) ^ rx) << 3) + (col & 7)] = f2bf(pv[nt]);
      }
      if (l15 == 0) {
        const int q = q0 + row;
        mpart[((size_t)b * NKB + kb) * PP + q] = m;
        lpart[((size_t)b * NKB + kb) * PP + q] = e;
      }
    }
  }
  __syncthreads();
  {
    const int row = tid >> 2;       // 0..127
    const int qtr = tid & 3;        // 32-col quarter
    const int rx = row & 15;
    const ushort_t* srcr = Pt + row * 128;
    ushort_t* dst = Pbuf + ((size_t)b * PP + q0 + row) * PP + k0 + qtr * 32;
#pragma unroll
    for (int j = 0; j < 4; ++j) {
      u16x8 v = *(const u16x8*)(srcr + (((qtr * 4 + j) ^ rx) << 3));
      *(u16x8*)(dst + j * 8) = v;
    }
  }
}

// ---------------------------------------------------------------------------
// Stats reduce: alpha[b][kb][q] = exp(m_kb - M) / L
// ---------------------------------------------------------------------------
__global__ __launch_bounds__(256) void stats_kernel(
    const float* __restrict__ mpart, const float* __restrict__ lpart,
    float* __restrict__ alphab) {
  const int q = blockIdx.x * 256 + threadIdx.x;
  const int b = blockIdx.y;
  float m[NKB];
  float M = -3.0e38f;
#pragma unroll
  for (int kb = 0; kb < NKB; ++kb) {
    m[kb] = mpart[((size_t)b * NKB + kb) * PP + q];
    M = fmaxf(M, m[kb]);
  }
  float L = 0.f;
#pragma unroll
  for (int kb = 0; kb < NKB; ++kb)
    L += __expf(m[kb] - M) * lpart[((size_t)b * NKB + kb) * PP + q];
  const float rL = 1.f / L;
#pragma unroll
  for (int kb = 0; kb < NKB; ++kb)
    alphab[((size_t)b * NKB + kb) * PP + q] = __expf(m[kb] - M) * rL;
}

// ---------------------------------------------------------------------------
// PV-GEMM: out[gb][c][q] = sum_kb alpha[q][kb] * sum_{k in kb} P[q][k]*V[c][k]
// Pure bf16 MFMA inner loop. Templated on group size GBT: grid 36 x 4 x GBT,
// XCD chunk = 144*GBT/8 (each XCD owns whole batches -> V slice L2-fits).
// ---------------------------------------------------------------------------
template <int GBT>
__global__ __launch_bounds__(256, 3) void pv_kernel(
    const ushort_t* __restrict__ Pb, const ushort_t* __restrict__ Vb,
    const float* __restrict__ alphab, float* __restrict__ out, int bbase) {
  // ---- XCD bijective chunk swizzle (grid 36*4*GBT, %8 == 0) ----
  const int lin = blockIdx.x + 36 * blockIdx.y + 144 * blockIdx.z;
  const int o = (lin & 7) * (144 * GBT / 8) + (lin >> 3);
  const int b = o / 144;
  const int m0 = (o % 36) * 64;          // q
  const int n0 = ((o / 36) % 4) * 128;   // channel

  const int gb = bbase + b;
  const int tid = threadIdx.x;
  const int lane = tid & 63;
  const int w = tid >> 6;
  const int l15 = lane & 15;
  const int quad = lane >> 4;
  const int wm = w & 1;
  const int wn = w >> 1;

  __shared__ __align__(16) ushort_t Plds[2][64][64];  // 16 KB
  __shared__ __align__(16) ushort_t Vt[2][128][64];   // 32 KB

  f32x4 acc[2][4] = {};

  const ushort_t* P_base = Pb + ((size_t)b * PP + m0) * PP;
  const ushort_t* V_base = Vb + ((size_t)gb * CRD + n0) * PP;
  const float* a_base =
      alphab + (size_t)b * NKB * PP + m0 + wm * 32 + quad * 4;

  const int lr = lane >> 3;  // row-in-8-group
  const int lc = lane & 7;   // 16B chunk 0..7

  auto stage = [&](int kb, int buf) {
#pragma unroll
    for (int j = 0; j < 2; ++j) {
      const int row = w * 16 + j * 8 + lr;
      const int ch = lc ^ (row & 7);
      async16(P_base + (size_t)row * PP + kb * 64 + ch * 8,
              &Plds[buf][w * 16 + j * 8][0]);
    }
#pragma unroll
    for (int j = 0; j < 4; ++j) {
      const int row = w * 32 + j * 8 + lr;
      const int ch = lc ^ (row & 7);
      async16(V_base + (size_t)row * PP + kb * 64 + ch * 8,
              &Vt[buf][w * 32 + j * 8][0]);
    }
  };

  stage(0, 0);
  __syncthreads();

  for (int kb = 0; kb < NKB; ++kb) {
    const int buf = kb & 1;
    if (kb + 1 < NKB) stage(kb + 1, buf ^ 1);

    f32x4 av[2];
#pragma unroll
    for (int mt = 0; mt < 2; ++mt)
      av[mt] = *(const f32x4*)(a_base + (size_t)kb * PP + mt * 16);

    f32x4 pacc[2][4] = {};
#pragma unroll
    for (int h = 0; h < 2; ++h) {
      bf16x8 pa[2], vf[4];
#pragma unroll
      for (int mt = 0; mt < 2; ++mt) {
        const int row = wm * 32 + mt * 16 + l15;
        const int g = (h * 4 + quad) ^ (row & 7);
        pa[mt] = load_bf8(&Plds[buf][row][g * 8]);
      }
#pragma unroll
      for (int nt = 0; nt < 4; ++nt) {
        const int row = wn * 64 + nt * 16 + l15;
        const int g = (h * 4 + quad) ^ (row & 7);
        vf[nt] = load_bf8(&Vt[buf][row][g * 8]);
      }
#pragma unroll
      for (int mt = 0; mt < 2; ++mt)
#pragma unroll
        for (int nt = 0; nt < 4; ++nt)
          pacc[mt][nt] = MFMA16(pa[mt], vf[nt], pacc[mt][nt]);
    }

#pragma unroll
    for (int mt = 0; mt < 2; ++mt)
#pragma unroll
      for (int nt = 0; nt < 4; ++nt)
        acc[mt][nt] += av[mt] * pacc[mt][nt];

    __syncthreads();
  }

  // epilogue: alpha already includes 1/L. out[gb][c][q].
#pragma unroll
  for (int mt = 0; mt < 2; ++mt) {
    const int q = m0 + wm * 32 + mt * 16 + quad * 4;
#pragma unroll
    for (int nt = 0; nt < 4; ++nt) {
      const int ch = n0 + wn * 64 + nt * 16 + l15;
      *(f32x4*)(out + ((size_t)gb * CRD + ch) * PP + q) = acc[mt][nt];
    }
  }
}

// ---------------------------------------------------------------------------
// Fallback fused attention for small workspaces.
// ---------------------------------------------------------------------------
__global__ __launch_bounds__(256, 2) void attn_direct_kernel(
    const ushort_t* __restrict__ Qh, const ushort_t* __restrict__ Ql,
    const ushort_t* __restrict__ Kh, const ushort_t* __restrict__ Kl,
    const ushort_t* __restrict__ Vb, float* __restrict__ out) {
  const int b = blockIdx.z;
  const int qb = blockIdx.x;
  const int tid = threadIdx.x;
  const int lane = tid & 63;
  const int w = tid >> 6;
  const int l15 = lane & 15;
  const int quad = lane >> 4;

  __shared__ __align__(16) ushort_t Kbuf[2][2][16][520];
  __shared__ __align__(16) ushort_t P_lds[4][16][40];

  bf16x8 qh[8], ql[8];
  {
    const size_t qrow = ((size_t)b * PP + qb * 64 + w * 16 + l15) * HIDD;
#pragma unroll
    for (int ks = 0; ks < 8; ++ks) {
      qh[ks] = load_bf8(Qh + qrow + ks * 32 + quad * 8);
      ql[ks] = load_bf8(Ql + qrow + ks * 32 + quad * 8);
    }
  }

  f32x4 o_acc[32] = {};
  float m_run[4] = {-3.0e38f, -3.0e38f, -3.0e38f, -3.0e38f};
  float l_run[4] = {0.f, 0.f, 0.f, 0.f};

  const ushort_t* Kb[2] = {Kh + (size_t)b * PP * HIDD,
                           Kl + (size_t)b * PP * HIDD};
  const ushort_t* vbase = Vb + ((size_t)b * CRD + l15) * PP + quad * 8;

  auto stage = [&](int t, int buf) {
#pragma unroll
    for (int j = 0; j < 8; ++j) {
      const int idx = w * 8 + j;
      const int hl = idx >> 4;
      const int pair = idx & 15;
      const ushort_t* src =
          Kb[hl] + ((size_t)(t * 32 + pair * 2)) * HIDD + lane * 8;
      async16(src, &Kbuf[buf][hl][pair][0]);
    }
  };

  stage(0, 0);
  __syncthreads();

  for (int t = 0; t < PP / 32; ++t) {
    const int buf = t & 1;
    if (t + 1 < PP / 32) stage(t + 1, buf ^ 1);

    f32x4 sa0 = {}, sa1 = {};
#pragma unroll
    for (int ks = 0; ks < 8; ++ks) {
      const int co = (l15 & 1) * 256 + ks * 32 + quad * 8;
      bf16x8 kh0 = load_bf8(&Kbuf[buf][0][(l15 >> 1)][co]);
      bf16x8 kl0 = load_bf8(&Kbuf[buf][1][(l15 >> 1)][co]);
      bf16x8 kh1 = load_bf8(&Kbuf[buf][0][8 + (l15 >> 1)][co]);
      bf16x8 kl1 = load_bf8(&Kbuf[buf][1][8 + (l15 >> 1)][co]);
      sa0 = MFMA16(qh[ks], kh0, sa0);
      sa1 = MFMA16(qh[ks], kh1, sa1);
      sa0 = MFMA16(ql[ks], kh0, sa0);
      sa1 = MFMA16(ql[ks], kh1, sa1);
      sa0 = MFMA16(qh[ks], kl0, sa0);
      sa1 = MFMA16(qh[ks], kl1, sa1);
    }

    float mx[4], al[4], p0[4], p1[4], rs[4];
#pragma unroll
    for (int r = 0; r < 4; ++r) mx[r] = fmaxf(sa0[r], sa1[r]);
#pragma unroll
    for (int d = 1; d < 16; d <<= 1)
#pragma unroll
      for (int r = 0; r < 4; ++r) mx[r] = fmaxf(mx[r], __shfl_xor(mx[r], d));
#pragma unroll
    for (int r = 0; r < 4; ++r) {
      const float mnew = fmaxf(m_run[r], mx[r]);
      al[r] = __expf(m_run[r] - mnew);
      m_run[r] = mnew;
      p0[r] = __expf(sa0[r] - mnew);
      p1[r] = __expf(sa1[r] - mnew);
      rs[r] = p0[r] + p1[r];
    }
#pragma unroll
    for (int d = 1; d < 16; d <<= 1)
#pragma unroll
      for (int r = 0; r < 4; ++r) rs[r] += __shfl_xor(rs[r], d);
#pragma unroll
    for (int r = 0; r < 4; ++r) l_run[r] = l_run[r] * al[r] + rs[r];

#pragma unroll
    for (int r = 0; r < 4; ++r) {
      P_lds[w][quad * 4 + r][l15] = f2bf(p0[r]);
      P_lds[w][quad * 4 + r][16 + l15] = f2bf(p1[r]);
    }
    asm volatile("s_waitcnt lgkmcnt(0)" ::: "memory");
    bf16x8 pa = load_bf8(&P_lds[w][l15][quad * 8]);

#pragma unroll
    for (int nt = 0; nt < 32; ++nt)
#pragma unroll
      for (int r = 0; r < 4; ++r) o_acc[nt][r] *= al[r];

    const ushort_t* vt = vbase + t * 32;
#pragma unroll
    for (int nt = 0; nt < 32; ++nt) {
      bf16x8 vfr = load_bf8(vt + (size_t)nt * 16 * PP);
      o_acc[nt] = MFMA16(pa, vfr, o_acc[nt]);
    }
    __syncthreads();
  }

  float rl[4];
#pragma unroll
  for (int r = 0; r < 4; ++r) rl[r] = 1.f / l_run[r];
  const int q0 = qb * 64 + w * 16 + quad * 4;
#pragma unroll
  for (int nt = 0; nt < 32; ++nt) {
    const int c = nt * 16 + l15;
    float* op = out + ((size_t)b * CRD + c) * PP + q0;
#pragma unroll
    for (int r = 0; r < 4; ++r) op[r] = o_acc[nt][r] * rl[r];
  }
}

// ---------------------------------------------------------------------------
extern "C" void kernel_launch(void* const* d_in, const int* in_sizes, int n_in,
                              void* d_out, int out_size, void* d_ws,
                              size_t ws_size, hipStream_t stream) {
  (void)in_sizes; (void)n_in; (void)out_size;

  const float* Xq = (const float*)d_in[0];
  const float* Xr = (const float*)d_in[1];
  const float* Wq = (const float*)d_in[2];
  const float* bq = (const float*)d_in[3];
  const float* Wk = (const float*)d_in[4];
  const float* bk = (const float*)d_in[5];
  float* out = (float*)d_out;

  const size_t nQK = (size_t)BB * PP * HIDD;  // 4.72M elems
  const size_t nV = (size_t)BB * CRD * PP;    // 9.44M elems

  ushort_t* p = (ushort_t*)d_ws;
  ushort_t* Qh = p; p += nQK;
  ushort_t* Ql = p; p += nQK;
  ushort_t* Kh = p; p += nQK;
  ushort_t* Kl = p; p += nQK;
  ushort_t* Vb = p; p += nV;
  ushort_t* scratch = p;

  // proj view of scratch (transient, used before attn phase):
  ushort_t* Xth = scratch;
  ushort_t* Xtl = Xth + (size_t)BB * PP * CQD;
  ushort_t* Wh2 = Xtl + (size_t)BB * PP * CQD;
  ushort_t* Wl2 = Wh2 + (size_t)HIDD * CQD;
  char* proj_end = (char*)(Wl2 + (size_t)HIDD * CQD);

  // attn view of scratch, parameterized by group size gb:
  auto attn_layout = [&](int gb, ushort_t*& Pb, float*& mp, float*& lp,
                         float*& al) -> char* {
    Pb = scratch;
    mp = (float*)(Pb + (size_t)gb * PP * PP);
    lp = mp + (size_t)gb * NKB * PP;
    al = lp + (size_t)gb * NKB * PP;
    return (char*)(al + (size_t)gb * NKB * PP);
  };

  ushort_t *Pb8, *Pb4;
  float *mp8, *lp8, *al8, *mp4, *lp4, *al4;
  char* attn8_end = attn_layout(8, Pb8, mp8, lp8, al8);
  char* attn4_end = attn_layout(4, Pb4, mp4, lp4, al4);

  char* end8 = proj_end > attn8_end ? proj_end : attn8_end;
  char* end4 = proj_end > attn4_end ? proj_end : attn4_end;
  const size_t needed8 = (size_t)(end8 - (char*)d_ws);
  const size_t needed4 = (size_t)(end4 - (char*)d_ws);

  if (ws_size >= needed4) {
    // ---- projection phase (shared by both attn variants) ----
    wcast_kernel<<<dim3(HIDD * CQD / 2048), 256, 0, stream>>>(Wq, Wh2, Wl2);
    tcast_kernel<CQD, false><<<dim3(PP / 64, CQD / 64, BB), 256, 0, stream>>>(
        Xq, Xth, Xtl, nullptr);
    projgemm_kernel<CQD><<<dim3(BB * PP / 128, HIDD / 64), 256, 0, stream>>>(
        Wh2, Wl2, Xth, Xtl, bq, Qh, Ql);

    wcast_kernel<<<dim3(HIDD * CRD / 2048), 256, 0, stream>>>(Wk, Wh2, Wl2);
    tcast_kernel<CRD, true><<<dim3(PP / 64, CRD / 64, BB), 256, 0, stream>>>(
        Xr, Xth, Xtl, Vb);
    projgemm_kernel<CRD><<<dim3(BB * PP / 128, HIDD / 64), 256, 0, stream>>>(
        Wh2, Wl2, Xth, Xtl, bk, Kh, Kl);

    if (ws_size >= needed8) {
      // ---- single-group attention: 1 sgemm + 1 stats + 1 pv ----
      sgemm_kernel<8><<<dim3(18, 18, 8), 512, 0, stream>>>(
          Qh, Ql, Kh, Kl, Pb8, mp8, lp8, 0);
      stats_kernel<<<dim3(PP / 256, 8), 256, 0, stream>>>(mp8, lp8, al8);
      pv_kernel<8><<<dim3(36, 4, 8), 256, 0, stream>>>(Pb8, Vb, al8, out, 0);
    } else {
      // ---- two-group attention (round-9 proven path) ----
      for (int g = 0; g < BB / 4; ++g) {
        const int bbase = g * 4;
        sgemm_kernel<4><<<dim3(18, 18, 4), 512, 0, stream>>>(
            Qh, Ql, Kh, Kl, Pb4, mp4, lp4, bbase);
        stats_kernel<<<dim3(PP / 256, 4), 256, 0, stream>>>(mp4, lp4, al4);
        pv_kernel<4><<<dim3(36, 4, 4), 256, 0, stream>>>(Pb4, Vb, al4, out,
                                                         bbase);
      }
    }
  } else {
    proj_kernel<CQD><<<dim3(4, PP / 64, BB), 256, 0, stream>>>(Xq, Wq, bq, Qh,
                                                               Ql);
    proj_kernel<CRD><<<dim3(4, PP / 64, BB), 256, 0, stream>>>(Xr, Wk, bk, Kh,
                                                               Kl);
    cast_v_kernel<<<dim3(nV / 1024), 256, 0, stream>>>(Xr, Vb);
    attn_direct_kernel<<<dim3(PP / 64, 1, BB), 256, 0, stream>>>(
        Qh, Ql, Kh, Kl, Vb, out);
  }
}